// Round 7
// baseline (386.776 us; speedup 1.0000x reference)
//
#include <hip/hip_runtime.h>
#include <hip/hip_bf16.h>

typedef unsigned short u16;
typedef unsigned int   u32;
typedef __bf16 bf16_t;
typedef bf16_t bf16x8 __attribute__((ext_vector_type(8)));
typedef u16    u16x8  __attribute__((ext_vector_type(8)));
typedef float  f32x4  __attribute__((ext_vector_type(4)));

#define DIM  2048
#define SEQ  2048
#define BATCH 2
#define NH   32
#define NKVH 8
#define HD   64
#define KVDIM (NKVH*HD)   // 512
#define NQKV (DIM + 2*KVDIM)  // 3072
#define SCALE 0.125f

__device__ __forceinline__ float b2f(u16 u) {
  union { u32 i; float f; } v; v.i = ((u32)u) << 16; return v.f;
}
__device__ __forceinline__ u16 f2b(float f) {
  union { float f; u32 i; } v; v.f = f;
  u32 x = v.i;
  return (u16)((x + 0x7fffu + ((x >> 16) & 1u)) >> 16);  // RNE
}
__device__ __forceinline__ u32 pkbf2(float a, float b) {  // low=a, high=b
  __hip_bfloat162 h = __float22bfloat162_rn(float2{a, b});
  union { __hip_bfloat162 h; u32 u; } v; v.h = h; return v.u;
}
__device__ __forceinline__ int probe_bf16(const u32* probe) { return probe[0] != 0u; }
__device__ __forceinline__ float ext_ld(const void* p, long idx, int mode_bf16) {
  return mode_bf16 ? b2f(((const u16*)p)[idx]) : ((const float*)p)[idx];
}
// 4 consecutive table values (fp32 float4 / bf16 ushort4); idx multiple of 4.
__device__ __forceinline__ f32x4 ld4(const void* p, long idx, int mode_bf16) {
  f32x4 r;
  if (mode_bf16) {
    ushort4 v = *(const ushort4*)((const u16*)p + idx);
    r[0] = b2f(v.x); r[1] = b2f(v.y); r[2] = b2f(v.z); r[3] = b2f(v.w);
  } else {
    float4 v = *(const float4*)((const float*)p + idx);
    r[0] = v.x; r[1] = v.y; r[2] = v.z; r[3] = v.w;
  }
  return r;
}
__device__ __forceinline__ void gload_lds16(const u16* g, u16* l) {
  __builtin_amdgcn_global_load_lds((const __attribute__((address_space(1))) void*)g,
                                   (__attribute__((address_space(3))) void*)l, 16, 0, 0);
}

// ---------------- merged prep: W transposes + x cast, one launch.
__global__ void prep(const void* __restrict__ Wq, const void* __restrict__ Wk,
                     const void* __restrict__ Wv, const void* __restrict__ Wo,
                     const void* __restrict__ x, u16* __restrict__ WqkvT,
                     u16* __restrict__ WoT, u16* __restrict__ xb, int use_xb,
                     const u32* __restrict__ probe) {
  int mode = probe_bf16(probe);
  int xt = blockIdx.x;
  int tx = threadIdx.x, ty = threadIdx.y;   // (32,8)
  if (xt < 160) {
    __shared__ u16 t[32][33];
    const void* in; int C, c0, obase; u16* out; int ld;
    if (xt < 64)       { in = Wq; C = DIM;   c0 = xt * 32;        obase = 0;           out = WqkvT; ld = DIM; }
    else if (xt < 80)  { in = Wk; C = KVDIM; c0 = (xt - 64) * 32; obase = DIM;         out = WqkvT; ld = DIM; }
    else if (xt < 96)  { in = Wv; C = KVDIM; c0 = (xt - 80) * 32; obase = DIM + KVDIM; out = WqkvT; ld = DIM; }
    else               { in = Wo; C = DIM;   c0 = (xt - 96) * 32; obase = 0;           out = WoT;   ld = DIM; }
    int r0 = blockIdx.y * 32;
#pragma unroll
    for (int i = 0; i < 32; i += 8)
      t[ty + i][tx] = mode ? ((const u16*)in)[(long)(r0 + ty + i) * C + c0 + tx]
                           : f2b(((const float*)in)[(long)(r0 + ty + i) * C + c0 + tx]);
    __syncthreads();
#pragma unroll
    for (int i = 0; i < 32; i += 8)
      out[(long)(obase + c0 + ty + i) * ld + r0 + tx] = t[tx][ty + i];
  } else {
    if (mode || !use_xb) return;
    int tid = ty * 32 + tx;
    long base = ((long)((xt - 160) * 64 + blockIdx.y) * 256 + tid) * 8;
    float4 f0 = *(const float4*)((const float*)x + base);
    float4 f1 = *(const float4*)((const float*)x + base + 4);
    u16x8 t8;
    t8[0] = f2b(f0.x); t8[1] = f2b(f0.y); t8[2] = f2b(f0.z); t8[3] = f2b(f0.w);
    t8[4] = f2b(f1.x); t8[5] = f2b(f1.y); t8[6] = f2b(f1.z); t8[7] = f2b(f1.w);
    *(u16x8*)&xb[base] = t8;
  }
}

// ======== 128x128 GEMM (BK=32, 4 waves, 4x4 MFMA/wave), XOR-swizzled LDS ========
// SINGLE swapped kloop (n in reg dim). Q/K epilogue: FUSED RoPE (pair (d,d+32) =
// (acc[mi][ni], acc[mi][ni+2]) same thread; one cos + one sin vector load per
// (mi,ni)). Q scaled by 1/8. V epilogue: scalar stores (32B-coalesced per group).

__launch_bounds__(256)
__global__ void gemm_qkv(const void* __restrict__ x, const u16* __restrict__ xb,
                         int use_xb, const u16* __restrict__ Bt,
                         u16* __restrict__ Qb, u16* __restrict__ Kb, u16* __restrict__ Vt,
                         const void* __restrict__ cosb, const void* __restrict__ sinb,
                         const u32* __restrict__ probe) {
  int pmode = probe_bf16(probe);
  int mode = (use_xb || pmode) ? 1 : 0;
  const u16* A16 = pmode ? (const u16*)x : xb;
  const float* Af = (const float*)x;
  __shared__ __align__(16) u16 As[128 * 32];
  __shared__ __align__(16) u16 Bs[128 * 32];
  int tid = threadIdx.x, lane = tid & 63, wv = tid >> 6;
  int l16 = lane & 15, q = lane >> 4;
  int bm0 = blockIdx.y * 128, bn0 = blockIdx.x * 128;
  int mbase = (wv & 1) * 64, nbase = (wv >> 1) * 64;
  int c0 = tid, c1 = tid + 256;
  int r0 = c0 >> 2, s0 = (c0 & 3) ^ ((r0 >> 1) & 3);
  int r1 = c1 >> 2, s1 = (c1 & 3) ^ ((r1 >> 1) & 3);
  const int K = DIM;
  long aoff0 = (long)(bm0 + r0) * K + s0 * 8;
  long aoff1 = (long)(bm0 + r1) * K + s1 * 8;
  long boff0 = (long)(bn0 + r0) * K + s0 * 8;
  long boff1 = (long)(bn0 + r1) * K + s1 * 8;
  int rsw = (q ^ ((l16 >> 1) & 3)) * 8;
  f32x4 acc[4][4] = {};

  for (int k0 = 0; k0 < K; k0 += 32) {
    __syncthreads();
    if (mode) {
      gload_lds16(A16 + aoff0 + k0, &As[wv * 512]);
      gload_lds16(A16 + aoff1 + k0, &As[2048 + wv * 512]);
    } else {
      float4 f0 = *(const float4*)(Af + aoff0 + k0);
      float4 f1 = *(const float4*)(Af + aoff0 + k0 + 4);
      u16x8 t;
      t[0] = f2b(f0.x); t[1] = f2b(f0.y); t[2] = f2b(f0.z); t[3] = f2b(f0.w);
      t[4] = f2b(f1.x); t[5] = f2b(f1.y); t[6] = f2b(f1.z); t[7] = f2b(f1.w);
      *(u16x8*)&As[c0 * 8] = t;
      float4 g0 = *(const float4*)(Af + aoff1 + k0);
      float4 g1 = *(const float4*)(Af + aoff1 + k0 + 4);
      u16x8 u;
      u[0] = f2b(g0.x); u[1] = f2b(g0.y); u[2] = f2b(g0.z); u[3] = f2b(g0.w);
      u[4] = f2b(g1.x); u[5] = f2b(g1.y); u[6] = f2b(g1.z); u[7] = f2b(g1.w);
      *(u16x8*)&As[c1 * 8] = u;
    }
    gload_lds16(Bt + boff0 + k0, &Bs[wv * 512]);
    gload_lds16(Bt + boff1 + k0, &Bs[2048 + wv * 512]);
    __syncthreads();
    bf16x8 af[4], bfr[4];
#pragma unroll
    for (int mi = 0; mi < 4; mi++)
      af[mi] = *(const bf16x8*)&As[(mbase + mi * 16 + l16) * 32 + rsw];
#pragma unroll
    for (int ni = 0; ni < 4; ni++)
      bfr[ni] = *(const bf16x8*)&Bs[(nbase + ni * 16 + l16) * 32 + rsw];
#pragma unroll
    for (int mi = 0; mi < 4; mi++)
#pragma unroll
      for (int ni = 0; ni < 4; ni++)
        acc[mi][ni] = __builtin_amdgcn_mfma_f32_16x16x32_bf16(
            bfr[ni], af[mi], acc[mi][ni], 0, 0, 0);   // swapped: n in reg dim
  }

  if (bn0 < DIM + KVDIM) {   // Q or K block: fused RoPE epilogue
    u16* Cb; int ldc, ncol0; float osc;
    if (bn0 < DIM) { Cb = Qb; ldc = DIM; ncol0 = bn0; osc = SCALE; }
    else           { Cb = Kb; ldc = KVDIM; ncol0 = bn0 - DIM; osc = 1.0f; }
#pragma unroll
    for (int mi = 0; mi < 4; mi++) {
      int m = bm0 + mbase + mi * 16 + l16;
      int st = m & (SEQ - 1);
#pragma unroll
      for (int ni = 0; ni < 2; ni++) {
        int dl = ni * 16 + q * 4;            // d in [0,32), 4 consecutive
        f32x4 c4 = ld4(cosb, (long)st * HD + dl, pmode);
        f32x4 s4 = ld4(sinb, (long)st * HD + dl, pmode);
        float lo[4], hi[4];
#pragma unroll
        for (int r = 0; r < 4; r++) {
          float a = acc[mi][ni][r], b = acc[mi][ni + 2][r];
          lo[r] = (a * c4[r] - b * s4[r]) * osc;
          hi[r] = (b * c4[r] + a * s4[r]) * osc;
        }
        int n0 = ncol0 + nbase + dl;
        uint2 w0, w1;
        w0.x = pkbf2(lo[0], lo[1]); w0.y = pkbf2(lo[2], lo[3]);
        w1.x = pkbf2(hi[0], hi[1]); w1.y = pkbf2(hi[2], hi[3]);
        *(uint2*)&Cb[(long)m * ldc + n0]      = w0;
        *(uint2*)&Cb[(long)m * ldc + n0 + 32] = w1;
      }
    }
  } else {                   // V block: transposed into Vt(B,KVH,64,S)
    int vcol0 = bn0 - DIM - KVDIM;
#pragma unroll
    for (int mi = 0; mi < 4; mi++) {
      int m = bm0 + mbase + mi * 16 + l16;
      int bb = m >> 11, s = m & (SEQ - 1);
#pragma unroll
      for (int ni = 0; ni < 4; ni++) {
        int vcol = vcol0 + nbase + ni * 16 + q * 4;
        int kvh2 = vcol >> 6, d = vcol & 63;
        long vb = ((long)(bb * NKVH + kvh2) * HD + d) * SEQ + s;
#pragma unroll
        for (int r = 0; r < 4; r++)
          Vt[vb + (long)r * SEQ] = f2b(acc[mi][ni][r]);
      }
    }
  }
}

// output projection: AO[M,2048] bf16 * WoT[2048,2048]^T -> C (ext dtype)
__launch_bounds__(256)
__global__ void gemm_ao(const u16* __restrict__ A, const u16* __restrict__ Bt,
                        void* __restrict__ C, const u32* __restrict__ probe) {
  int mode = probe_bf16(probe);
  __shared__ __align__(16) u16 As[128 * 32];
  __shared__ __align__(16) u16 Bs[128 * 32];
  int tid = threadIdx.x, lane = tid & 63, wv = tid >> 6;
  int l16 = lane & 15, q = lane >> 4;
  int bm0 = blockIdx.y * 128, bn0 = blockIdx.x * 128;
  int mbase = (wv & 1) * 64, nbase = (wv >> 1) * 64;
  int c0 = tid, c1 = tid + 256;
  int r0 = c0 >> 2, s0 = (c0 & 3) ^ ((r0 >> 1) & 3);
  int r1 = c1 >> 2, s1 = (c1 & 3) ^ ((r1 >> 1) & 3);
  const int K = DIM;
  long aoff0 = (long)(bm0 + r0) * K + s0 * 8;
  long aoff1 = (long)(bm0 + r1) * K + s1 * 8;
  long boff0 = (long)(bn0 + r0) * K + s0 * 8;
  long boff1 = (long)(bn0 + r1) * K + s1 * 8;
  int rsw = (q ^ ((l16 >> 1) & 3)) * 8;
  f32x4 acc[4][4] = {};
  for (int k0 = 0; k0 < K; k0 += 32) {
    __syncthreads();
    gload_lds16(A + aoff0 + k0, &As[wv * 512]);
    gload_lds16(A + aoff1 + k0, &As[2048 + wv * 512]);
    gload_lds16(Bt + boff0 + k0, &Bs[wv * 512]);
    gload_lds16(Bt + boff1 + k0, &Bs[2048 + wv * 512]);
    __syncthreads();
    bf16x8 af[4], bfr[4];
#pragma unroll
    for (int mi = 0; mi < 4; mi++)
      af[mi] = *(const bf16x8*)&As[(mbase + mi * 16 + l16) * 32 + rsw];
#pragma unroll
    for (int ni = 0; ni < 4; ni++)
      bfr[ni] = *(const bf16x8*)&Bs[(nbase + ni * 16 + l16) * 32 + rsw];
#pragma unroll
    for (int mi = 0; mi < 4; mi++)
#pragma unroll
      for (int ni = 0; ni < 4; ni++)
        acc[mi][ni] = __builtin_amdgcn_mfma_f32_16x16x32_bf16(
            bfr[ni], af[mi], acc[mi][ni], 0, 0, 0);   // swapped: n in reg dim
  }
#pragma unroll
  for (int mi = 0; mi < 4; mi++)
#pragma unroll
    for (int ni = 0; ni < 4; ni++) {
      int m = bm0 + mbase + mi * 16 + l16;
      int n0 = bn0 + nbase + ni * 16 + q * 4;
      if (mode) {
        uint2 w;
        w.x = pkbf2(acc[mi][ni][0], acc[mi][ni][1]);
        w.y = pkbf2(acc[mi][ni][2], acc[mi][ni][3]);
        *(uint2*)&((u16*)C)[(long)m * DIM + n0] = w;
      } else {
        float4 f;
        f.x = acc[mi][ni][0]; f.y = acc[mi][ni][1];
        f.z = acc[mi][ni][2]; f.w = acc[mi][ni][3];
        *(float4*)&((float*)C)[(long)m * DIM + n0] = f;
      }
    }
}

// ---------------- fused causal attention, BARRIER-FREE (guide lesson #7).
// K/V per (b,kvh) = 512 KB, L2/L3-resident; per-tile fragments (16 KB) fit L1
// and all 4 waves read IDENTICAL K/V fragments -> wave 0 warms L1, rest hit.
// MFMA B-operands load DIRECTLY from global: K[s][d] is 16B-contiguous in d,
// Vt[d][s] is 16B-contiguous in s -- one 16B load per lane per fragment.
// No LDS staging, no double-buffer, no __syncthreads: waves fully independent
// (masked tiles exit via break). Ps = per-wave LDS scratch (same-wave RAW only).
// QBLK=128 (4 waves x 32 q-rows), grid (8, B*NH), diagonal pair {i, 15-i}.
__launch_bounds__(256)
__global__ void attn_kernel(const u16* __restrict__ Q, const u16* __restrict__ K,
                            const u16* __restrict__ Vt, u16* __restrict__ AO) {
  __shared__ __align__(16) u16 Ps[4][32 * 64];   // per-wave P scratch, 16 KB
  int tid = threadIdx.x, lane = tid & 63, wv = tid >> 6;
  int l16 = lane & 15, q = lane >> 4;
  int i = blockIdx.x;          // 0..7
  int bh = blockIdx.y;
  int b = bh >> 5, h = bh & 31, kvh = h >> 2;
  const u16* Kp = K + (long)b * SEQ * KVDIM + kvh * HD;
  const u16* Vp = Vt + (long)(b * NKVH + kvh) * HD * SEQ;

  int e = l16 & 7;
  int off0 = (q ^ e) * 8;          // Ps logical block hh=0 (elems 0..31)
  int off1 = ((4 + q) ^ e) * 8;    // Ps logical block hh=1 (elems 32..63)

  bf16x8 ones;
#pragma unroll
  for (int j = 0; j < 8; j++) ones[j] = (bf16_t)1.0f;

#pragma unroll
  for (int ph = 0; ph < 2; ph++) {
    int t = ph ? (15 - i) : i;
    int qbase = t * 128 + wv * 32;
    const u16* Qp = Q + (long)(b * SEQ + qbase) * DIM + h * HD;
    bf16x8 aq[2][2];
#pragma unroll
    for (int qr = 0; qr < 2; qr++) {
      aq[qr][0] = *(const bf16x8*)&Qp[(qr * 16 + l16) * DIM + q * 8];
      aq[qr][1] = *(const bf16x8*)&Qp[(qr * 16 + l16) * DIM + 32 + q * 8];
    }
    f32x4 o_acc[2][4] = {};
    f32x4 l_acc[2] = {};
    int nkt = 2 * (t + 1);
    int wmax = qbase + 31;       // wave's last q-row

    for (int kt = 0; kt < nkt; kt++) {
      int kk = kt * 64;
      if (kk > wmax) break;      // later tiles also masked; no barriers to keep
      // ---- K fragments direct from global (row = kv, 16B contiguous in d)
      bf16x8 bk[4][2];
#pragma unroll
      for (int ni = 0; ni < 4; ni++) {
        const u16* kr = Kp + (long)(kk + ni * 16 + l16) * KVDIM;
        bk[ni][0] = *(const bf16x8*)&kr[q * 8];
        bk[ni][1] = *(const bf16x8*)&kr[32 + q * 8];
      }
      // ---- QK^T for both qr halves (S^T: reg=kv, lane=qrow)
      f32x4 sc[2][4];
#pragma unroll
      for (int qr = 0; qr < 2; qr++) {
        int qb16 = qbase + qr * 16;
        if (kk > qb16 + 15) continue;   // half fully masked
#pragma unroll
        for (int ni = 0; ni < 4; ni++) {
          f32x4 z = {};
          z = __builtin_amdgcn_mfma_f32_16x16x32_bf16(bk[ni][0], aq[qr][0], z, 0, 0, 0);
          z = __builtin_amdgcn_mfma_f32_16x16x32_bf16(bk[ni][1], aq[qr][1], z, 0, 0, 0);
          sc[qr][ni] = z;
        }
      }
      // ---- V fragments direct from global (row = d, 16B contiguous in s)
      bf16x8 bv[4][2];
#pragma unroll
      for (int di = 0; di < 4; di++) {
        const u16* vr = Vp + (long)(di * 16 + l16) * SEQ + kk;
        bv[di][0] = *(const bf16x8*)&vr[q * 8];
        bv[di][1] = *(const bf16x8*)&vr[32 + q * 8];
      }
      bool diag = (kt >= 2 * t);
#pragma unroll
      for (int qr = 0; qr < 2; qr++) {
        int qb16 = qbase + qr * 16;
        if (kk > qb16 + 15) continue;
        int qrow = qb16 + l16;
        if (diag) {
#pragma unroll
          for (int ni = 0; ni < 4; ni++)
#pragma unroll
            for (int r = 0; r < 4; r++) {
              int kv = kk + ni * 16 + q * 4 + r;
              float p = __expf(sc[qr][ni][r]);
              sc[qr][ni][r] = (kv <= qrow) ? p : 0.f;
            }
        } else {
#pragma unroll
          for (int ni = 0; ni < 4; ni++)
#pragma unroll
            for (int r = 0; r < 4; r++) sc[qr][ni][r] = __expf(sc[qr][ni][r]);
        }
        // P store (swizzled 8B) then A-fragment read (same-wave RAW, no barrier)
#pragma unroll
        for (int ni = 0; ni < 4; ni++) {
          uint2 w;
          w.x = pkbf2(sc[qr][ni][0], sc[qr][ni][1]);
          w.y = pkbf2(sc[qr][ni][2], sc[qr][ni][3]);
          int pblk = (2 * ni + (q >> 1)) ^ e;
          *(uint2*)&Ps[wv][(qr * 16 + l16) * 64 + pblk * 8 + (q & 1) * 4] = w;
        }
        bf16x8 ap0 = *(const bf16x8*)&Ps[wv][(qr * 16 + l16) * 64 + off0];
        bf16x8 ap1 = *(const bf16x8*)&Ps[wv][(qr * 16 + l16) * 64 + off1];
        l_acc[qr] = __builtin_amdgcn_mfma_f32_16x16x32_bf16(ap0, ones, l_acc[qr], 0, 0, 0);
        l_acc[qr] = __builtin_amdgcn_mfma_f32_16x16x32_bf16(ap1, ones, l_acc[qr], 0, 0, 0);
#pragma unroll
        for (int di = 0; di < 4; di++) {
          o_acc[qr][di] = __builtin_amdgcn_mfma_f32_16x16x32_bf16(ap0, bv[di][0], o_acc[qr][di], 0, 0, 0);
          o_acc[qr][di] = __builtin_amdgcn_mfma_f32_16x16x32_bf16(ap1, bv[di][1], o_acc[qr][di], 0, 0, 0);
        }
      }
    }
#pragma unroll
    for (int qr = 0; qr < 2; qr++) {
      long obase = (long)(b * SEQ + qbase + qr * 16 + q * 4) * DIM + h * HD;
#pragma unroll
      for (int r = 0; r < 4; r++) {
        float inv = 1.0f / l_acc[qr][r];
#pragma unroll
        for (int di = 0; di < 4; di++)
          AO[obase + (long)r * DIM + di * 16 + l16] = f2b(o_acc[qr][di][r] * inv);
      }
    }
  }
}

extern "C" void kernel_launch(void* const* d_in, const int* in_sizes, int n_in,
                              void* d_out, int out_size, void* d_ws, size_t ws_size,
                              hipStream_t stream) {
  const void* x    = d_in[0];
  const void* Wq   = d_in[1];
  const void* Wk   = d_in[2];
  const void* Wv   = d_in[3];
  const void* Wo   = d_in[4];
  const void* cosb = d_in[5];
  const void* sinb = d_in[6];
  const u32*  probe = (const u32*)d_in[7];

  // workspace: WqkvT 12M + WoT 8M + Qb 16M + Kb 4M + Vt 4M (=44M) + xb 16M opt
  u16* WqkvT = (u16*)d_ws;
  u16* WoT = WqkvT + (size_t)NQKV * DIM;
  u16* Qb  = WoT + (size_t)DIM * DIM;
  u16* Kb  = Qb  + (size_t)BATCH * SEQ * DIM;
  u16* Vt  = Kb  + (size_t)BATCH * SEQ * KVDIM;
  u16* xb  = Vt  + (size_t)BATCH * NKVH * HD * SEQ;
  u16* AO  = Qb;   // alias: each attn wave reads its own Q rows before writing them

  size_t need_xb = ((size_t)(xb - WqkvT) + (size_t)BATCH * SEQ * DIM) * sizeof(u16);
  int use_xb = ws_size >= need_xb;

  int M = BATCH * SEQ;  // 4096
  prep<<<dim3(224, 64), dim3(32, 8), 0, stream>>>(Wq, Wk, Wv, Wo, x, WqkvT, WoT,
                                                  xb, use_xb, probe);
  gemm_qkv<<<dim3(NQKV / 128, M / 128), 256, 0, stream>>>(x, xb, use_xb, WqkvT,
                                                          Qb, Kb, Vt, cosb, sinb, probe);

  attn_kernel<<<dim3(8, BATCH * NH), 256, 0, stream>>>(Qb, Kb, Vt, AO);

  gemm_ao<<<dim3(DIM / 128, M / 128), 256, 0, stream>>>(AO, WoT, d_out, probe);
}

// Round 8
// 322.355 us; speedup vs baseline: 1.1998x; 1.1998x over previous
//
#include <hip/hip_runtime.h>
#include <hip/hip_bf16.h>

typedef unsigned short u16;
typedef unsigned int   u32;
typedef __bf16 bf16_t;
typedef bf16_t bf16x8 __attribute__((ext_vector_type(8)));
typedef u16    u16x8  __attribute__((ext_vector_type(8)));
typedef float  f32x4  __attribute__((ext_vector_type(4)));

#define DIM  2048
#define SEQ  2048
#define BATCH 2
#define NH   32
#define NKVH 8
#define HD   64
#define KVDIM (NKVH*HD)   // 512
#define NQKV (DIM + 2*KVDIM)  // 3072
#define SCALE 0.125f

#define PRIO1()  __builtin_amdgcn_s_setprio(1)
#define PRIO0()  __builtin_amdgcn_s_setprio(0)

__device__ __forceinline__ float b2f(u16 u) {
  union { u32 i; float f; } v; v.i = ((u32)u) << 16; return v.f;
}
__device__ __forceinline__ u16 f2b(float f) {
  union { float f; u32 i; } v; v.f = f;
  u32 x = v.i;
  return (u16)((x + 0x7fffu + ((x >> 16) & 1u)) >> 16);  // RNE
}
__device__ __forceinline__ u32 pkbf2(float a, float b) {  // low=a, high=b
  __hip_bfloat162 h = __float22bfloat162_rn(float2{a, b});
  union { __hip_bfloat162 h; u32 u; } v; v.h = h; return v.u;
}
__device__ __forceinline__ int probe_bf16(const u32* probe) { return probe[0] != 0u; }
__device__ __forceinline__ float ext_ld(const void* p, long idx, int mode_bf16) {
  return mode_bf16 ? b2f(((const u16*)p)[idx]) : ((const float*)p)[idx];
}
// 4 consecutive table values (fp32 float4 / bf16 ushort4); idx multiple of 4.
__device__ __forceinline__ f32x4 ld4(const void* p, long idx, int mode_bf16) {
  f32x4 r;
  if (mode_bf16) {
    ushort4 v = *(const ushort4*)((const u16*)p + idx);
    r[0] = b2f(v.x); r[1] = b2f(v.y); r[2] = b2f(v.z); r[3] = b2f(v.w);
  } else {
    float4 v = *(const float4*)((const float*)p + idx);
    r[0] = v.x; r[1] = v.y; r[2] = v.z; r[3] = v.w;
  }
  return r;
}
__device__ __forceinline__ void gload_lds16(const u16* g, u16* l) {
  __builtin_amdgcn_global_load_lds((const __attribute__((address_space(1))) void*)g,
                                   (__attribute__((address_space(3))) void*)l, 16, 0, 0);
}

// ---------------- merged prep: W transposes + x cast, one launch.
__global__ void prep(const void* __restrict__ Wq, const void* __restrict__ Wk,
                     const void* __restrict__ Wv, const void* __restrict__ Wo,
                     const void* __restrict__ x, u16* __restrict__ WqkvT,
                     u16* __restrict__ WoT, u16* __restrict__ xb, int use_xb,
                     const u32* __restrict__ probe) {
  int mode = probe_bf16(probe);
  int xt = blockIdx.x;
  int tx = threadIdx.x, ty = threadIdx.y;   // (32,8)
  if (xt < 160) {
    __shared__ u16 t[32][33];
    const void* in; int C, c0, obase; u16* out; int ld;
    if (xt < 64)       { in = Wq; C = DIM;   c0 = xt * 32;        obase = 0;           out = WqkvT; ld = DIM; }
    else if (xt < 80)  { in = Wk; C = KVDIM; c0 = (xt - 64) * 32; obase = DIM;         out = WqkvT; ld = DIM; }
    else if (xt < 96)  { in = Wv; C = KVDIM; c0 = (xt - 80) * 32; obase = DIM + KVDIM; out = WqkvT; ld = DIM; }
    else               { in = Wo; C = DIM;   c0 = (xt - 96) * 32; obase = 0;           out = WoT;   ld = DIM; }
    int r0 = blockIdx.y * 32;
#pragma unroll
    for (int i = 0; i < 32; i += 8)
      t[ty + i][tx] = mode ? ((const u16*)in)[(long)(r0 + ty + i) * C + c0 + tx]
                           : f2b(((const float*)in)[(long)(r0 + ty + i) * C + c0 + tx]);
    __syncthreads();
#pragma unroll
    for (int i = 0; i < 32; i += 8)
      out[(long)(obase + c0 + ty + i) * ld + r0 + tx] = t[tx][ty + i];
  } else {
    if (mode || !use_xb) return;
    int tid = ty * 32 + tx;
    long base = ((long)((xt - 160) * 64 + blockIdx.y) * 256 + tid) * 8;
    float4 f0 = *(const float4*)((const float*)x + base);
    float4 f1 = *(const float4*)((const float*)x + base + 4);
    u16x8 t8;
    t8[0] = f2b(f0.x); t8[1] = f2b(f0.y); t8[2] = f2b(f0.z); t8[3] = f2b(f0.w);
    t8[4] = f2b(f1.x); t8[5] = f2b(f1.y); t8[6] = f2b(f1.z); t8[7] = f2b(f1.w);
    *(u16x8*)&xb[base] = t8;
  }
}

// ======== 128x128 GEMM (BK=32, 4 waves, 4x4 MFMA/wave), XOR-swizzled LDS ========
// SINGLE swapped kloop (n in reg dim). Q/K epilogue: FUSED RoPE (pair (d,d+32) =
// (acc[mi][ni], acc[mi][ni+2]) same thread; one cos + one sin vector load per
// (mi,ni)). Q scaled by 1/8. V epilogue: scalar stores (32B-coalesced per group).

__launch_bounds__(256)
__global__ void gemm_qkv(const void* __restrict__ x, const u16* __restrict__ xb,
                         int use_xb, const u16* __restrict__ Bt,
                         u16* __restrict__ Qb, u16* __restrict__ Kb, u16* __restrict__ Vt,
                         const void* __restrict__ cosb, const void* __restrict__ sinb,
                         const u32* __restrict__ probe) {
  int pmode = probe_bf16(probe);
  int mode = (use_xb || pmode) ? 1 : 0;
  const u16* A16 = pmode ? (const u16*)x : xb;
  const float* Af = (const float*)x;
  __shared__ __align__(16) u16 As[128 * 32];
  __shared__ __align__(16) u16 Bs[128 * 32];
  int tid = threadIdx.x, lane = tid & 63, wv = tid >> 6;
  int l16 = lane & 15, q = lane >> 4;
  int bm0 = blockIdx.y * 128, bn0 = blockIdx.x * 128;
  int mbase = (wv & 1) * 64, nbase = (wv >> 1) * 64;
  int c0 = tid, c1 = tid + 256;
  int r0 = c0 >> 2, s0 = (c0 & 3) ^ ((r0 >> 1) & 3);
  int r1 = c1 >> 2, s1 = (c1 & 3) ^ ((r1 >> 1) & 3);
  const int K = DIM;
  long aoff0 = (long)(bm0 + r0) * K + s0 * 8;
  long aoff1 = (long)(bm0 + r1) * K + s1 * 8;
  long boff0 = (long)(bn0 + r0) * K + s0 * 8;
  long boff1 = (long)(bn0 + r1) * K + s1 * 8;
  int rsw = (q ^ ((l16 >> 1) & 3)) * 8;
  f32x4 acc[4][4] = {};

  for (int k0 = 0; k0 < K; k0 += 32) {
    __syncthreads();
    if (mode) {
      gload_lds16(A16 + aoff0 + k0, &As[wv * 512]);
      gload_lds16(A16 + aoff1 + k0, &As[2048 + wv * 512]);
    } else {
      float4 f0 = *(const float4*)(Af + aoff0 + k0);
      float4 f1 = *(const float4*)(Af + aoff0 + k0 + 4);
      u16x8 t;
      t[0] = f2b(f0.x); t[1] = f2b(f0.y); t[2] = f2b(f0.z); t[3] = f2b(f0.w);
      t[4] = f2b(f1.x); t[5] = f2b(f1.y); t[6] = f2b(f1.z); t[7] = f2b(f1.w);
      *(u16x8*)&As[c0 * 8] = t;
      float4 g0 = *(const float4*)(Af + aoff1 + k0);
      float4 g1 = *(const float4*)(Af + aoff1 + k0 + 4);
      u16x8 u;
      u[0] = f2b(g0.x); u[1] = f2b(g0.y); u[2] = f2b(g0.z); u[3] = f2b(g0.w);
      u[4] = f2b(g1.x); u[5] = f2b(g1.y); u[6] = f2b(g1.z); u[7] = f2b(g1.w);
      *(u16x8*)&As[c1 * 8] = u;
    }
    gload_lds16(Bt + boff0 + k0, &Bs[wv * 512]);
    gload_lds16(Bt + boff1 + k0, &Bs[2048 + wv * 512]);
    __syncthreads();
    bf16x8 af[4], bfr[4];
#pragma unroll
    for (int mi = 0; mi < 4; mi++)
      af[mi] = *(const bf16x8*)&As[(mbase + mi * 16 + l16) * 32 + rsw];
#pragma unroll
    for (int ni = 0; ni < 4; ni++)
      bfr[ni] = *(const bf16x8*)&Bs[(nbase + ni * 16 + l16) * 32 + rsw];
#pragma unroll
    for (int mi = 0; mi < 4; mi++)
#pragma unroll
      for (int ni = 0; ni < 4; ni++)
        acc[mi][ni] = __builtin_amdgcn_mfma_f32_16x16x32_bf16(
            bfr[ni], af[mi], acc[mi][ni], 0, 0, 0);   // swapped: n in reg dim
  }

  if (bn0 < DIM + KVDIM) {   // Q or K block: fused RoPE epilogue
    u16* Cb; int ldc, ncol0; float osc;
    if (bn0 < DIM) { Cb = Qb; ldc = DIM; ncol0 = bn0; osc = SCALE; }
    else           { Cb = Kb; ldc = KVDIM; ncol0 = bn0 - DIM; osc = 1.0f; }
#pragma unroll
    for (int mi = 0; mi < 4; mi++) {
      int m = bm0 + mbase + mi * 16 + l16;
      int st = m & (SEQ - 1);
#pragma unroll
      for (int ni = 0; ni < 2; ni++) {
        int dl = ni * 16 + q * 4;            // d in [0,32), 4 consecutive
        f32x4 c4 = ld4(cosb, (long)st * HD + dl, pmode);
        f32x4 s4 = ld4(sinb, (long)st * HD + dl, pmode);
        float lo[4], hi[4];
#pragma unroll
        for (int r = 0; r < 4; r++) {
          float a = acc[mi][ni][r], b = acc[mi][ni + 2][r];
          lo[r] = (a * c4[r] - b * s4[r]) * osc;
          hi[r] = (b * c4[r] + a * s4[r]) * osc;
        }
        int n0 = ncol0 + nbase + dl;
        uint2 w0, w1;
        w0.x = pkbf2(lo[0], lo[1]); w0.y = pkbf2(lo[2], lo[3]);
        w1.x = pkbf2(hi[0], hi[1]); w1.y = pkbf2(hi[2], hi[3]);
        *(uint2*)&Cb[(long)m * ldc + n0]      = w0;
        *(uint2*)&Cb[(long)m * ldc + n0 + 32] = w1;
      }
    }
  } else {                   // V block: transposed into Vt(B,KVH,64,S)
    int vcol0 = bn0 - DIM - KVDIM;
#pragma unroll
    for (int mi = 0; mi < 4; mi++) {
      int m = bm0 + mbase + mi * 16 + l16;
      int bb = m >> 11, s = m & (SEQ - 1);
#pragma unroll
      for (int ni = 0; ni < 4; ni++) {
        int vcol = vcol0 + nbase + ni * 16 + q * 4;
        int kvh2 = vcol >> 6, d = vcol & 63;
        long vb = ((long)(bb * NKVH + kvh2) * HD + d) * SEQ + s;
#pragma unroll
        for (int r = 0; r < 4; r++)
          Vt[vb + (long)r * SEQ] = f2b(acc[mi][ni][r]);
      }
    }
  }
}

// output projection: AO[M,2048] bf16 * WoT[2048,2048]^T -> C (ext dtype)
__launch_bounds__(256)
__global__ void gemm_ao(const u16* __restrict__ A, const u16* __restrict__ Bt,
                        void* __restrict__ C, const u32* __restrict__ probe) {
  int mode = probe_bf16(probe);
  __shared__ __align__(16) u16 As[128 * 32];
  __shared__ __align__(16) u16 Bs[128 * 32];
  int tid = threadIdx.x, lane = tid & 63, wv = tid >> 6;
  int l16 = lane & 15, q = lane >> 4;
  int bm0 = blockIdx.y * 128, bn0 = blockIdx.x * 128;
  int mbase = (wv & 1) * 64, nbase = (wv >> 1) * 64;
  int c0 = tid, c1 = tid + 256;
  int r0 = c0 >> 2, s0 = (c0 & 3) ^ ((r0 >> 1) & 3);
  int r1 = c1 >> 2, s1 = (c1 & 3) ^ ((r1 >> 1) & 3);
  const int K = DIM;
  long aoff0 = (long)(bm0 + r0) * K + s0 * 8;
  long aoff1 = (long)(bm0 + r1) * K + s1 * 8;
  long boff0 = (long)(bn0 + r0) * K + s0 * 8;
  long boff1 = (long)(bn0 + r1) * K + s1 * 8;
  int rsw = (q ^ ((l16 >> 1) & 3)) * 8;
  f32x4 acc[4][4] = {};
  for (int k0 = 0; k0 < K; k0 += 32) {
    __syncthreads();
    gload_lds16(A + aoff0 + k0, &As[wv * 512]);
    gload_lds16(A + aoff1 + k0, &As[2048 + wv * 512]);
    gload_lds16(Bt + boff0 + k0, &Bs[wv * 512]);
    gload_lds16(Bt + boff1 + k0, &Bs[2048 + wv * 512]);
    __syncthreads();
    bf16x8 af[4], bfr[4];
#pragma unroll
    for (int mi = 0; mi < 4; mi++)
      af[mi] = *(const bf16x8*)&As[(mbase + mi * 16 + l16) * 32 + rsw];
#pragma unroll
    for (int ni = 0; ni < 4; ni++)
      bfr[ni] = *(const bf16x8*)&Bs[(nbase + ni * 16 + l16) * 32 + rsw];
#pragma unroll
    for (int mi = 0; mi < 4; mi++)
#pragma unroll
      for (int ni = 0; ni < 4; ni++)
        acc[mi][ni] = __builtin_amdgcn_mfma_f32_16x16x32_bf16(
            bfr[ni], af[mi], acc[mi][ni], 0, 0, 0);   // swapped: n in reg dim
  }
#pragma unroll
  for (int mi = 0; mi < 4; mi++)
#pragma unroll
    for (int ni = 0; ni < 4; ni++) {
      int m = bm0 + mbase + mi * 16 + l16;
      int n0 = bn0 + nbase + ni * 16 + q * 4;
      if (mode) {
        uint2 w;
        w.x = pkbf2(acc[mi][ni][0], acc[mi][ni][1]);
        w.y = pkbf2(acc[mi][ni][2], acc[mi][ni][3]);
        *(uint2*)&((u16*)C)[(long)m * DIM + n0] = w;
      } else {
        float4 f;
        f.x = acc[mi][ni][0]; f.y = acc[mi][ni][1];
        f.z = acc[mi][ni][2]; f.w = acc[mi][ni][3];
        *(float4*)&((float*)C)[(long)m * DIM + n0] = f;
      }
    }
}

// ---------------- fused causal attention, QBLK=128 (4 waves x 32 q-rows).
// R6 known-good staged structure + T5 setprio around MFMA clusters.
// grid (8, B*NH), diagonal pair {i, 15-i}; 34 kv-tiles per block (balanced).
// Double-buffered staging: one barrier per tile, stage(kt+1) before compute(kt).
// LDS: Ks 16K + Vs 16K + Ps 16K = 48 KB; grid 512 = 2 blocks/CU -> the two
// independent blocks per CU are at different phases; setprio lets the CU favor
// the MFMA-issuing block (m191 attn regime: +4-7%; NOT the m190 lockstep null).
__launch_bounds__(256, 2)
__global__ void attn_kernel(const u16* __restrict__ Q, const u16* __restrict__ K,
                            const u16* __restrict__ Vt, u16* __restrict__ AO) {
  __shared__ __align__(16) u16 Ks[2 * 64 * 64];  // [buf][kv][d] swizzled
  __shared__ __align__(16) u16 Vs[2 * 64 * 64];  // [buf][d][kv] swizzled
  __shared__ __align__(16) u16 Ps[4][32 * 64];   // per-wave P (2 qr halves)
  int tid = threadIdx.x, lane = tid & 63, wv = tid >> 6;
  int l16 = lane & 15, q = lane >> 4;
  int i = blockIdx.x;          // 0..7
  int bh = blockIdx.y;
  int b = bh >> 5, h = bh & 31, kvh = h >> 2;
  const u16* Kp = K + (long)b * SEQ * KVDIM + kvh * HD;
  const u16* Vp = Vt + (long)(b * NKVH + kvh) * HD * SEQ;

  int cA = tid, cB = tid + 256;
  int rA = cA >> 3, bA = (cA & 7) ^ (rA & 7);
  int rB = cB >> 3, bB = (cB & 7) ^ (rB & 7);
  const u16* kSrcA = Kp + (long)rA * KVDIM + bA * 8;
  const u16* kSrcB = Kp + (long)rB * KVDIM + bB * 8;
  const u16* vSrcA = Vp + (long)rA * SEQ + bA * 8;
  const u16* vSrcB = Vp + (long)rB * SEQ + bB * 8;
  u16* kDstA = &Ks[(wv * 64 + lane) * 8];        // + buf offset (0 or 4096)
  u16* kDstB = &Ks[(256 + wv * 64 + lane) * 8];
  u16* vDstA = &Vs[(wv * 64 + lane) * 8];
  u16* vDstB = &Vs[(256 + wv * 64 + lane) * 8];

  int e = l16 & 7;
  int off0 = (q ^ e) * 8;          // logical block hh=0 (elems 0..31)
  int off1 = ((4 + q) ^ e) * 8;    // logical block hh=1 (elems 32..63)

  bf16x8 ones;
#pragma unroll
  for (int j = 0; j < 8; j++) ones[j] = (bf16_t)1.0f;

#pragma unroll
  for (int ph = 0; ph < 2; ph++) {
    int t = ph ? (15 - i) : i;
    int qbase = t * 128 + wv * 32;
    const u16* Qp = Q + (long)(b * SEQ + qbase) * DIM + h * HD;
    bf16x8 aq[2][2];
#pragma unroll
    for (int qr = 0; qr < 2; qr++) {
      aq[qr][0] = *(const bf16x8*)&Qp[(qr * 16 + l16) * DIM + q * 8];
      aq[qr][1] = *(const bf16x8*)&Qp[(qr * 16 + l16) * DIM + 32 + q * 8];
    }
    f32x4 o_acc[2][4] = {};
    f32x4 l_acc[2] = {};
    int nkt = 2 * (t + 1);
    int wmax = qbase + 31;       // wave's last q-row

    __syncthreads();   // all waves done reading LDS from previous phase
    gload_lds16(kSrcA, kDstA);
    gload_lds16(kSrcB, kDstB);
    gload_lds16(vSrcA, vDstA);
    gload_lds16(vSrcB, vDstB);
    int curo = 0;

    for (int kt = 0; kt < nkt; kt++) {
      __syncthreads();   // drains vmcnt: buf[curo] staged; prev reads complete
      if (kt + 1 < nkt) {   // stage next tile into the other buffer
        long kk2 = (long)(kt + 1) * 64;
        int nxt = curo ^ 4096;
        gload_lds16(kSrcA + kk2 * KVDIM, kDstA + nxt);
        gload_lds16(kSrcB + kk2 * KVDIM, kDstB + nxt);
        gload_lds16(vSrcA + kk2, vDstA + nxt);
        gload_lds16(vSrcB + kk2, vDstB + nxt);
      }
      int kk = kt * 64;
      if (kk > wmax) { curo ^= 4096; continue; }   // wave fully masked (uniform)
      const u16* Ksb = &Ks[curo];
      const u16* Vsb = &Vs[curo];

      bf16x8 bk[4][2], bv[4][2];
#pragma unroll
      for (int ni = 0; ni < 4; ni++) {
        bk[ni][0] = *(const bf16x8*)&Ksb[(ni * 16 + l16) * 64 + off0];
        bk[ni][1] = *(const bf16x8*)&Ksb[(ni * 16 + l16) * 64 + off1];
      }
#pragma unroll
      for (int di = 0; di < 4; di++) {
        bv[di][0] = *(const bf16x8*)&Vsb[(di * 16 + l16) * 64 + off0];
        bv[di][1] = *(const bf16x8*)&Vsb[(di * 16 + l16) * 64 + off1];
      }
      bool diag = (kt >= 2 * t);
#pragma unroll
      for (int qr = 0; qr < 2; qr++) {
        int qb16 = qbase + qr * 16;
        if (kk > qb16 + 15) continue;   // half fully masked (uniform per wave)
        f32x4 sc[4];
        PRIO1();
#pragma unroll
        for (int ni = 0; ni < 4; ni++) {
          f32x4 z = {};
          z = __builtin_amdgcn_mfma_f32_16x16x32_bf16(bk[ni][0], aq[qr][0], z, 0, 0, 0);
          z = __builtin_amdgcn_mfma_f32_16x16x32_bf16(bk[ni][1], aq[qr][1], z, 0, 0, 0);
          sc[ni] = z;
        }
        PRIO0();
        int qrow = qb16 + l16;
        if (diag) {
#pragma unroll
          for (int ni = 0; ni < 4; ni++)
#pragma unroll
            for (int r = 0; r < 4; r++) {
              int kv = kk + ni * 16 + q * 4 + r;
              float p = __expf(sc[ni][r]);
              sc[ni][r] = (kv <= qrow) ? p : 0.f;
            }
        } else {
#pragma unroll
          for (int ni = 0; ni < 4; ni++)
#pragma unroll
            for (int r = 0; r < 4; r++) sc[ni][r] = __expf(sc[ni][r]);
        }
#pragma unroll
        for (int ni = 0; ni < 4; ni++) {
          uint2 w;
          w.x = pkbf2(sc[ni][0], sc[ni][1]);
          w.y = pkbf2(sc[ni][2], sc[ni][3]);
          int pblk = (2 * ni + (q >> 1)) ^ e;
          *(uint2*)&Ps[wv][(qr * 16 + l16) * 64 + pblk * 8 + (q & 1) * 4] = w;
        }
        bf16x8 ap0 = *(const bf16x8*)&Ps[wv][(qr * 16 + l16) * 64 + off0];
        bf16x8 ap1 = *(const bf16x8*)&Ps[wv][(qr * 16 + l16) * 64 + off1];
        PRIO1();
        l_acc[qr] = __builtin_amdgcn_mfma_f32_16x16x32_bf16(ap0, ones, l_acc[qr], 0, 0, 0);
        l_acc[qr] = __builtin_amdgcn_mfma_f32_16x16x32_bf16(ap1, ones, l_acc[qr], 0, 0, 0);
#pragma unroll
        for (int di = 0; di < 4; di++) {
          o_acc[qr][di] = __builtin_amdgcn_mfma_f32_16x16x32_bf16(ap0, bv[di][0], o_acc[qr][di], 0, 0, 0);
          o_acc[qr][di] = __builtin_amdgcn_mfma_f32_16x16x32_bf16(ap1, bv[di][1], o_acc[qr][di], 0, 0, 0);
        }
        PRIO0();
      }
      curo ^= 4096;
    }
#pragma unroll
    for (int qr = 0; qr < 2; qr++) {
      long obase = (long)(b * SEQ + qbase + qr * 16 + q * 4) * DIM + h * HD;
#pragma unroll
      for (int r = 0; r < 4; r++) {
        float inv = 1.0f / l_acc[qr][r];
#pragma unroll
        for (int di = 0; di < 4; di++)
          AO[obase + (long)r * DIM + di * 16 + l16] = f2b(o_acc[qr][di][r] * inv);
      }
    }
  }
}

extern "C" void kernel_launch(void* const* d_in, const int* in_sizes, int n_in,
                              void* d_out, int out_size, void* d_ws, size_t ws_size,
                              hipStream_t stream) {
  const void* x    = d_in[0];
  const void* Wq   = d_in[1];
  const void* Wk   = d_in[2];
  const void* Wv   = d_in[3];
  const void* Wo   = d_in[4];
  const void* cosb = d_in[5];
  const void* sinb = d_in[6];
  const u32*  probe = (const u32*)d_in[7];

  // workspace: WqkvT 12M + WoT 8M + Qb 16M + Kb 4M + Vt 4M (=44M) + xb 16M opt
  u16* WqkvT = (u16*)d_ws;
  u16* WoT = WqkvT + (size_t)NQKV * DIM;
  u16* Qb  = WoT + (size_t)DIM * DIM;
  u16* Kb  = Qb  + (size_t)BATCH * SEQ * DIM;
  u16* Vt  = Kb  + (size_t)BATCH * SEQ * KVDIM;
  u16* xb  = Vt  + (size_t)BATCH * NKVH * HD * SEQ;
  u16* AO  = Qb;   // alias: each attn wave reads its own Q rows before writing them

  size_t need_xb = ((size_t)(xb - WqkvT) + (size_t)BATCH * SEQ * DIM) * sizeof(u16);
  int use_xb = ws_size >= need_xb;

  int M = BATCH * SEQ;  // 4096
  prep<<<dim3(224, 64), dim3(32, 8), 0, stream>>>(Wq, Wk, Wv, Wo, x, WqkvT, WoT,
                                                  xb, use_xb, probe);
  gemm_qkv<<<dim3(NQKV / 128, M / 128), 256, 0, stream>>>(x, xb, use_xb, WqkvT,
                                                          Qb, Kb, Vt, cosb, sinb, probe);

  attn_kernel<<<dim3(8, BATCH * NH), 256, 0, stream>>>(Qb, Kb, Vt, AO);

  gemm_ao<<<dim3(DIM / 128, M / 128), 256, 0, stream>>>(AO, WoT, d_out, probe);
}

// Round 9
// 319.335 us; speedup vs baseline: 1.2112x; 1.0095x over previous
//
#include <hip/hip_runtime.h>
#include <hip/hip_bf16.h>

typedef unsigned short u16;
typedef unsigned int   u32;
typedef __bf16 bf16_t;
typedef bf16_t bf16x8 __attribute__((ext_vector_type(8)));
typedef u16    u16x8  __attribute__((ext_vector_type(8)));
typedef float  f32x4  __attribute__((ext_vector_type(4)));

#define DIM  2048
#define SEQ  2048
#define BATCH 2
#define NH   32
#define NKVH 8
#define HD   64
#define KVDIM (NKVH*HD)   // 512
#define NQKV (DIM + 2*KVDIM)  // 3072
#define SCALE 0.125f

__device__ __forceinline__ float b2f(u16 u) {
  union { u32 i; float f; } v; v.i = ((u32)u) << 16; return v.f;
}
__device__ __forceinline__ u16 f2b(float f) {
  union { float f; u32 i; } v; v.f = f;
  u32 x = v.i;
  return (u16)((x + 0x7fffu + ((x >> 16) & 1u)) >> 16);  // RNE
}
__device__ __forceinline__ u32 pkbf2(float a, float b) {  // low=a, high=b
  __hip_bfloat162 h = __float22bfloat162_rn(float2{a, b});
  union { __hip_bfloat162 h; u32 u; } v; v.h = h; return v.u;
}
__device__ __forceinline__ int probe_bf16(const u32* probe) { return probe[0] != 0u; }
__device__ __forceinline__ float ext_ld(const void* p, long idx, int mode_bf16) {
  return mode_bf16 ? b2f(((const u16*)p)[idx]) : ((const float*)p)[idx];
}
// 4 consecutive table values (fp32 float4 / bf16 ushort4); idx multiple of 4.
__device__ __forceinline__ f32x4 ld4(const void* p, long idx, int mode_bf16) {
  f32x4 r;
  if (mode_bf16) {
    ushort4 v = *(const ushort4*)((const u16*)p + idx);
    r[0] = b2f(v.x); r[1] = b2f(v.y); r[2] = b2f(v.z); r[3] = b2f(v.w);
  } else {
    float4 v = *(const float4*)((const float*)p + idx);
    r[0] = v.x; r[1] = v.y; r[2] = v.z; r[3] = v.w;
  }
  return r;
}
__device__ __forceinline__ void gload_lds16(const u16* g, u16* l) {
  __builtin_amdgcn_global_load_lds((const __attribute__((address_space(1))) void*)g,
                                   (__attribute__((address_space(3))) void*)l, 16, 0, 0);
}

// ---------------- merged prep: W transposes + x cast, one launch.
__global__ void prep(const void* __restrict__ Wq, const void* __restrict__ Wk,
                     const void* __restrict__ Wv, const void* __restrict__ Wo,
                     const void* __restrict__ x, u16* __restrict__ WqkvT,
                     u16* __restrict__ WoT, u16* __restrict__ xb, int use_xb,
                     const u32* __restrict__ probe) {
  int mode = probe_bf16(probe);
  int xt = blockIdx.x;
  int tx = threadIdx.x, ty = threadIdx.y;   // (32,8)
  if (xt < 160) {
    __shared__ u16 t[32][33];
    const void* in; int C, c0, obase; u16* out; int ld;
    if (xt < 64)       { in = Wq; C = DIM;   c0 = xt * 32;        obase = 0;           out = WqkvT; ld = DIM; }
    else if (xt < 80)  { in = Wk; C = KVDIM; c0 = (xt - 64) * 32; obase = DIM;         out = WqkvT; ld = DIM; }
    else if (xt < 96)  { in = Wv; C = KVDIM; c0 = (xt - 80) * 32; obase = DIM + KVDIM; out = WqkvT; ld = DIM; }
    else               { in = Wo; C = DIM;   c0 = (xt - 96) * 32; obase = 0;           out = WoT;   ld = DIM; }
    int r0 = blockIdx.y * 32;
#pragma unroll
    for (int i = 0; i < 32; i += 8)
      t[ty + i][tx] = mode ? ((const u16*)in)[(long)(r0 + ty + i) * C + c0 + tx]
                           : f2b(((const float*)in)[(long)(r0 + ty + i) * C + c0 + tx]);
    __syncthreads();
#pragma unroll
    for (int i = 0; i < 32; i += 8)
      out[(long)(obase + c0 + ty + i) * ld + r0 + tx] = t[tx][ty + i];
  } else {
    if (mode || !use_xb) return;
    int tid = ty * 32 + tx;
    long base = ((long)((xt - 160) * 64 + blockIdx.y) * 256 + tid) * 8;
    float4 f0 = *(const float4*)((const float*)x + base);
    float4 f1 = *(const float4*)((const float*)x + base + 4);
    u16x8 t8;
    t8[0] = f2b(f0.x); t8[1] = f2b(f0.y); t8[2] = f2b(f0.z); t8[3] = f2b(f0.w);
    t8[4] = f2b(f1.x); t8[5] = f2b(f1.y); t8[6] = f2b(f1.z); t8[7] = f2b(f1.w);
    *(u16x8*)&xb[base] = t8;
  }
}

// ======== 128x128 GEMM (BK=32, 4 waves, 4x4 MFMA/wave), XOR-swizzled LDS ========
// SINGLE swapped kloop (n in reg dim). Q/K epilogue: FUSED RoPE (pair (d,d+32) =
// (acc[mi][ni], acc[mi][ni+2]) same thread; one cos + one sin vector load per
// (mi,ni)). Q scaled by 1/8. V epilogue: scalar stores (32B-coalesced per group).

__launch_bounds__(256)
__global__ void gemm_qkv(const void* __restrict__ x, const u16* __restrict__ xb,
                         int use_xb, const u16* __restrict__ Bt,
                         u16* __restrict__ Qb, u16* __restrict__ Kb, u16* __restrict__ Vt,
                         const void* __restrict__ cosb, const void* __restrict__ sinb,
                         const u32* __restrict__ probe) {
  int pmode = probe_bf16(probe);
  int mode = (use_xb || pmode) ? 1 : 0;
  const u16* A16 = pmode ? (const u16*)x : xb;
  const float* Af = (const float*)x;
  __shared__ __align__(16) u16 As[128 * 32];
  __shared__ __align__(16) u16 Bs[128 * 32];
  int tid = threadIdx.x, lane = tid & 63, wv = tid >> 6;
  int l16 = lane & 15, q = lane >> 4;
  int bm0 = blockIdx.y * 128, bn0 = blockIdx.x * 128;
  int mbase = (wv & 1) * 64, nbase = (wv >> 1) * 64;
  int c0 = tid, c1 = tid + 256;
  int r0 = c0 >> 2, s0 = (c0 & 3) ^ ((r0 >> 1) & 3);
  int r1 = c1 >> 2, s1 = (c1 & 3) ^ ((r1 >> 1) & 3);
  const int K = DIM;
  long aoff0 = (long)(bm0 + r0) * K + s0 * 8;
  long aoff1 = (long)(bm0 + r1) * K + s1 * 8;
  long boff0 = (long)(bn0 + r0) * K + s0 * 8;
  long boff1 = (long)(bn0 + r1) * K + s1 * 8;
  int rsw = (q ^ ((l16 >> 1) & 3)) * 8;
  f32x4 acc[4][4] = {};

  for (int k0 = 0; k0 < K; k0 += 32) {
    __syncthreads();
    if (mode) {
      gload_lds16(A16 + aoff0 + k0, &As[wv * 512]);
      gload_lds16(A16 + aoff1 + k0, &As[2048 + wv * 512]);
    } else {
      float4 f0 = *(const float4*)(Af + aoff0 + k0);
      float4 f1 = *(const float4*)(Af + aoff0 + k0 + 4);
      u16x8 t;
      t[0] = f2b(f0.x); t[1] = f2b(f0.y); t[2] = f2b(f0.z); t[3] = f2b(f0.w);
      t[4] = f2b(f1.x); t[5] = f2b(f1.y); t[6] = f2b(f1.z); t[7] = f2b(f1.w);
      *(u16x8*)&As[c0 * 8] = t;
      float4 g0 = *(const float4*)(Af + aoff1 + k0);
      float4 g1 = *(const float4*)(Af + aoff1 + k0 + 4);
      u16x8 u;
      u[0] = f2b(g0.x); u[1] = f2b(g0.y); u[2] = f2b(g0.z); u[3] = f2b(g0.w);
      u[4] = f2b(g1.x); u[5] = f2b(g1.y); u[6] = f2b(g1.z); u[7] = f2b(g1.w);
      *(u16x8*)&As[c1 * 8] = u;
    }
    gload_lds16(Bt + boff0 + k0, &Bs[wv * 512]);
    gload_lds16(Bt + boff1 + k0, &Bs[2048 + wv * 512]);
    __syncthreads();
    bf16x8 af[4], bfr[4];
#pragma unroll
    for (int mi = 0; mi < 4; mi++)
      af[mi] = *(const bf16x8*)&As[(mbase + mi * 16 + l16) * 32 + rsw];
#pragma unroll
    for (int ni = 0; ni < 4; ni++)
      bfr[ni] = *(const bf16x8*)&Bs[(nbase + ni * 16 + l16) * 32 + rsw];
#pragma unroll
    for (int mi = 0; mi < 4; mi++)
#pragma unroll
      for (int ni = 0; ni < 4; ni++)
        acc[mi][ni] = __builtin_amdgcn_mfma_f32_16x16x32_bf16(
            bfr[ni], af[mi], acc[mi][ni], 0, 0, 0);   // swapped: n in reg dim
  }

  if (bn0 < DIM + KVDIM) {   // Q or K block: fused RoPE epilogue
    u16* Cb; int ldc, ncol0; float osc;
    if (bn0 < DIM) { Cb = Qb; ldc = DIM; ncol0 = bn0; osc = SCALE; }
    else           { Cb = Kb; ldc = KVDIM; ncol0 = bn0 - DIM; osc = 1.0f; }
#pragma unroll
    for (int mi = 0; mi < 4; mi++) {
      int m = bm0 + mbase + mi * 16 + l16;
      int st = m & (SEQ - 1);
#pragma unroll
      for (int ni = 0; ni < 2; ni++) {
        int dl = ni * 16 + q * 4;            // d in [0,32), 4 consecutive
        f32x4 c4 = ld4(cosb, (long)st * HD + dl, pmode);
        f32x4 s4 = ld4(sinb, (long)st * HD + dl, pmode);
        float lo[4], hi[4];
#pragma unroll
        for (int r = 0; r < 4; r++) {
          float a = acc[mi][ni][r], b = acc[mi][ni + 2][r];
          lo[r] = (a * c4[r] - b * s4[r]) * osc;
          hi[r] = (b * c4[r] + a * s4[r]) * osc;
        }
        int n0 = ncol0 + nbase + dl;
        uint2 w0, w1;
        w0.x = pkbf2(lo[0], lo[1]); w0.y = pkbf2(lo[2], lo[3]);
        w1.x = pkbf2(hi[0], hi[1]); w1.y = pkbf2(hi[2], hi[3]);
        *(uint2*)&Cb[(long)m * ldc + n0]      = w0;
        *(uint2*)&Cb[(long)m * ldc + n0 + 32] = w1;
      }
    }
  } else {                   // V block: transposed into Vt(B,KVH,64,S)
    int vcol0 = bn0 - DIM - KVDIM;
#pragma unroll
    for (int mi = 0; mi < 4; mi++) {
      int m = bm0 + mbase + mi * 16 + l16;
      int bb = m >> 11, s = m & (SEQ - 1);
#pragma unroll
      for (int ni = 0; ni < 4; ni++) {
        int vcol = vcol0 + nbase + ni * 16 + q * 4;
        int kvh2 = vcol >> 6, d = vcol & 63;
        long vb = ((long)(bb * NKVH + kvh2) * HD + d) * SEQ + s;
#pragma unroll
        for (int r = 0; r < 4; r++)
          Vt[vb + (long)r * SEQ] = f2b(acc[mi][ni][r]);
      }
    }
  }
}

// output projection: AO[M,2048] bf16 * WoT[2048,2048]^T -> C (ext dtype)
__launch_bounds__(256)
__global__ void gemm_ao(const u16* __restrict__ A, const u16* __restrict__ Bt,
                        void* __restrict__ C, const u32* __restrict__ probe) {
  int mode = probe_bf16(probe);
  __shared__ __align__(16) u16 As[128 * 32];
  __shared__ __align__(16) u16 Bs[128 * 32];
  int tid = threadIdx.x, lane = tid & 63, wv = tid >> 6;
  int l16 = lane & 15, q = lane >> 4;
  int bm0 = blockIdx.y * 128, bn0 = blockIdx.x * 128;
  int mbase = (wv & 1) * 64, nbase = (wv >> 1) * 64;
  int c0 = tid, c1 = tid + 256;
  int r0 = c0 >> 2, s0 = (c0 & 3) ^ ((r0 >> 1) & 3);
  int r1 = c1 >> 2, s1 = (c1 & 3) ^ ((r1 >> 1) & 3);
  const int K = DIM;
  long aoff0 = (long)(bm0 + r0) * K + s0 * 8;
  long aoff1 = (long)(bm0 + r1) * K + s1 * 8;
  long boff0 = (long)(bn0 + r0) * K + s0 * 8;
  long boff1 = (long)(bn0 + r1) * K + s1 * 8;
  int rsw = (q ^ ((l16 >> 1) & 3)) * 8;
  f32x4 acc[4][4] = {};
  for (int k0 = 0; k0 < K; k0 += 32) {
    __syncthreads();
    gload_lds16(A + aoff0 + k0, &As[wv * 512]);
    gload_lds16(A + aoff1 + k0, &As[2048 + wv * 512]);
    gload_lds16(Bt + boff0 + k0, &Bs[wv * 512]);
    gload_lds16(Bt + boff1 + k0, &Bs[2048 + wv * 512]);
    __syncthreads();
    bf16x8 af[4], bfr[4];
#pragma unroll
    for (int mi = 0; mi < 4; mi++)
      af[mi] = *(const bf16x8*)&As[(mbase + mi * 16 + l16) * 32 + rsw];
#pragma unroll
    for (int ni = 0; ni < 4; ni++)
      bfr[ni] = *(const bf16x8*)&Bs[(nbase + ni * 16 + l16) * 32 + rsw];
#pragma unroll
    for (int mi = 0; mi < 4; mi++)
#pragma unroll
      for (int ni = 0; ni < 4; ni++)
        acc[mi][ni] = __builtin_amdgcn_mfma_f32_16x16x32_bf16(
            bfr[ni], af[mi], acc[mi][ni], 0, 0, 0);   // swapped: n in reg dim
  }
#pragma unroll
  for (int mi = 0; mi < 4; mi++)
#pragma unroll
    for (int ni = 0; ni < 4; ni++) {
      int m = bm0 + mbase + mi * 16 + l16;
      int n0 = bn0 + nbase + ni * 16 + q * 4;
      if (mode) {
        uint2 w;
        w.x = pkbf2(acc[mi][ni][0], acc[mi][ni][1]);
        w.y = pkbf2(acc[mi][ni][2], acc[mi][ni][3]);
        *(uint2*)&((u16*)C)[(long)m * DIM + n0] = w;
      } else {
        float4 f;
        f.x = acc[mi][ni][0]; f.y = acc[mi][ni][1];
        f.z = acc[mi][ni][2]; f.w = acc[mi][ni][3];
        *(float4*)&((float*)C)[(long)m * DIM + n0] = f;
      }
    }
}

// ---------------- fused causal attention, QBLK=128 (4 waves x 32 q-rows).
// R6 best-measured configuration (319.1 us): double-buffered LDS K/V staging,
// one barrier per kv-tile, stage(kt+1) issued before compute(kt) so the vmcnt
// drain at the next barrier is covered by compute. No setprio (R8: neutral-neg;
// waves are barrier-locked per tile -> no role diversity for T5 to arbitrate).
// grid (8, B*NH), diagonal pair {i, 15-i}; 34 kv-tiles per block (balanced).
// LDS: Ks 16K + Vs 16K + Ps 16K = 48 KB; grid 512 = 2 blocks/CU.
__launch_bounds__(256, 2)
__global__ void attn_kernel(const u16* __restrict__ Q, const u16* __restrict__ K,
                            const u16* __restrict__ Vt, u16* __restrict__ AO) {
  __shared__ __align__(16) u16 Ks[2 * 64 * 64];  // [buf][kv][d] swizzled
  __shared__ __align__(16) u16 Vs[2 * 64 * 64];  // [buf][d][kv] swizzled
  __shared__ __align__(16) u16 Ps[4][32 * 64];   // per-wave P (2 qr halves)
  int tid = threadIdx.x, lane = tid & 63, wv = tid >> 6;
  int l16 = lane & 15, q = lane >> 4;
  int i = blockIdx.x;          // 0..7
  int bh = blockIdx.y;
  int b = bh >> 5, h = bh & 31, kvh = h >> 2;
  const u16* Kp = K + (long)b * SEQ * KVDIM + kvh * HD;
  const u16* Vp = Vt + (long)(b * NKVH + kvh) * HD * SEQ;

  int cA = tid, cB = tid + 256;
  int rA = cA >> 3, bA = (cA & 7) ^ (rA & 7);
  int rB = cB >> 3, bB = (cB & 7) ^ (rB & 7);
  const u16* kSrcA = Kp + (long)rA * KVDIM + bA * 8;
  const u16* kSrcB = Kp + (long)rB * KVDIM + bB * 8;
  const u16* vSrcA = Vp + (long)rA * SEQ + bA * 8;
  const u16* vSrcB = Vp + (long)rB * SEQ + bB * 8;
  u16* kDstA = &Ks[(wv * 64 + lane) * 8];        // + buf offset (0 or 4096)
  u16* kDstB = &Ks[(256 + wv * 64 + lane) * 8];
  u16* vDstA = &Vs[(wv * 64 + lane) * 8];
  u16* vDstB = &Vs[(256 + wv * 64 + lane) * 8];

  int e = l16 & 7;
  int off0 = (q ^ e) * 8;          // logical block hh=0 (elems 0..31)
  int off1 = ((4 + q) ^ e) * 8;    // logical block hh=1 (elems 32..63)

  bf16x8 ones;
#pragma unroll
  for (int j = 0; j < 8; j++) ones[j] = (bf16_t)1.0f;

#pragma unroll
  for (int ph = 0; ph < 2; ph++) {
    int t = ph ? (15 - i) : i;
    int qbase = t * 128 + wv * 32;
    const u16* Qp = Q + (long)(b * SEQ + qbase) * DIM + h * HD;
    bf16x8 aq[2][2];
#pragma unroll
    for (int qr = 0; qr < 2; qr++) {
      aq[qr][0] = *(const bf16x8*)&Qp[(qr * 16 + l16) * DIM + q * 8];
      aq[qr][1] = *(const bf16x8*)&Qp[(qr * 16 + l16) * DIM + 32 + q * 8];
    }
    f32x4 o_acc[2][4] = {};
    f32x4 l_acc[2] = {};
    int nkt = 2 * (t + 1);
    int wmax = qbase + 31;       // wave's last q-row

    __syncthreads();   // all waves done reading LDS from previous phase
    gload_lds16(kSrcA, kDstA);
    gload_lds16(kSrcB, kDstB);
    gload_lds16(vSrcA, vDstA);
    gload_lds16(vSrcB, vDstB);
    int curo = 0;

    for (int kt = 0; kt < nkt; kt++) {
      __syncthreads();   // drains vmcnt: buf[curo] staged; prev reads complete
      if (kt + 1 < nkt) {   // stage next tile into the other buffer
        long kk2 = (long)(kt + 1) * 64;
        int nxt = curo ^ 4096;
        gload_lds16(kSrcA + kk2 * KVDIM, kDstA + nxt);
        gload_lds16(kSrcB + kk2 * KVDIM, kDstB + nxt);
        gload_lds16(vSrcA + kk2, vDstA + nxt);
        gload_lds16(vSrcB + kk2, vDstB + nxt);
      }
      int kk = kt * 64;
      if (kk > wmax) { curo ^= 4096; continue; }   // wave fully masked (uniform)
      const u16* Ksb = &Ks[curo];
      const u16* Vsb = &Vs[curo];

      bf16x8 bk[4][2], bv[4][2];
#pragma unroll
      for (int ni = 0; ni < 4; ni++) {
        bk[ni][0] = *(const bf16x8*)&Ksb[(ni * 16 + l16) * 64 + off0];
        bk[ni][1] = *(const bf16x8*)&Ksb[(ni * 16 + l16) * 64 + off1];
      }
#pragma unroll
      for (int di = 0; di < 4; di++) {
        bv[di][0] = *(const bf16x8*)&Vsb[(di * 16 + l16) * 64 + off0];
        bv[di][1] = *(const bf16x8*)&Vsb[(di * 16 + l16) * 64 + off1];
      }
      bool diag = (kt >= 2 * t);
#pragma unroll
      for (int qr = 0; qr < 2; qr++) {
        int qb16 = qbase + qr * 16;
        if (kk > qb16 + 15) continue;   // half fully masked (uniform per wave)
        f32x4 sc[4];
#pragma unroll
        for (int ni = 0; ni < 4; ni++) {
          f32x4 z = {};
          z = __builtin_amdgcn_mfma_f32_16x16x32_bf16(bk[ni][0], aq[qr][0], z, 0, 0, 0);
          z = __builtin_amdgcn_mfma_f32_16x16x32_bf16(bk[ni][1], aq[qr][1], z, 0, 0, 0);
          sc[ni] = z;
        }
        int qrow = qb16 + l16;
        if (diag) {
#pragma unroll
          for (int ni = 0; ni < 4; ni++)
#pragma unroll
            for (int r = 0; r < 4; r++) {
              int kv = kk + ni * 16 + q * 4 + r;
              float p = __expf(sc[ni][r]);
              sc[ni][r] = (kv <= qrow) ? p : 0.f;
            }
        } else {
#pragma unroll
          for (int ni = 0; ni < 4; ni++)
#pragma unroll
            for (int r = 0; r < 4; r++) sc[ni][r] = __expf(sc[ni][r]);
        }
#pragma unroll
        for (int ni = 0; ni < 4; ni++) {
          uint2 w;
          w.x = pkbf2(sc[ni][0], sc[ni][1]);
          w.y = pkbf2(sc[ni][2], sc[ni][3]);
          int pblk = (2 * ni + (q >> 1)) ^ e;
          *(uint2*)&Ps[wv][(qr * 16 + l16) * 64 + pblk * 8 + (q & 1) * 4] = w;
        }
        bf16x8 ap0 = *(const bf16x8*)&Ps[wv][(qr * 16 + l16) * 64 + off0];
        bf16x8 ap1 = *(const bf16x8*)&Ps[wv][(qr * 16 + l16) * 64 + off1];
        l_acc[qr] = __builtin_amdgcn_mfma_f32_16x16x32_bf16(ap0, ones, l_acc[qr], 0, 0, 0);
        l_acc[qr] = __builtin_amdgcn_mfma_f32_16x16x32_bf16(ap1, ones, l_acc[qr], 0, 0, 0);
#pragma unroll
        for (int di = 0; di < 4; di++) {
          o_acc[qr][di] = __builtin_amdgcn_mfma_f32_16x16x32_bf16(ap0, bv[di][0], o_acc[qr][di], 0, 0, 0);
          o_acc[qr][di] = __builtin_amdgcn_mfma_f32_16x16x32_bf16(ap1, bv[di][1], o_acc[qr][di], 0, 0, 0);
        }
      }
      curo ^= 4096;
    }
#pragma unroll
    for (int qr = 0; qr < 2; qr++) {
      long obase = (long)(b * SEQ + qbase + qr * 16 + q * 4) * DIM + h * HD;
#pragma unroll
      for (int r = 0; r < 4; r++) {
        float inv = 1.0f / l_acc[qr][r];
#pragma unroll
        for (int di = 0; di < 4; di++)
          AO[obase + (long)r * DIM + di * 16 + l16] = f2b(o_acc[qr][di][r] * inv);
      }
    }
  }
}

extern "C" void kernel_launch(void* const* d_in, const int* in_sizes, int n_in,
                              void* d_out, int out_size, void* d_ws, size_t ws_size,
                              hipStream_t stream) {
  const void* x    = d_in[0];
  const void* Wq   = d_in[1];
  const void* Wk   = d_in[2];
  const void* Wv   = d_in[3];
  const void* Wo   = d_in[4];
  const void* cosb = d_in[5];
  const void* sinb = d_in[6];
  const u32*  probe = (const u32*)d_in[7];

  // workspace: WqkvT 12M + WoT 8M + Qb 16M + Kb 4M + Vt 4M (=44M) + xb 16M opt
  u16* WqkvT = (u16*)d_ws;
  u16* WoT = WqkvT + (size_t)NQKV * DIM;
  u16* Qb  = WoT + (size_t)DIM * DIM;
  u16* Kb  = Qb  + (size_t)BATCH * SEQ * DIM;
  u16* Vt  = Kb  + (size_t)BATCH * SEQ * KVDIM;
  u16* xb  = Vt  + (size_t)BATCH * NKVH * HD * SEQ;
  u16* AO  = Qb;   // alias: each attn wave reads its own Q rows before writing them

  size_t need_xb = ((size_t)(xb - WqkvT) + (size_t)BATCH * SEQ * DIM) * sizeof(u16);
  int use_xb = ws_size >= need_xb;

  int M = BATCH * SEQ;  // 4096
  prep<<<dim3(224, 64), dim3(32, 8), 0, stream>>>(Wq, Wk, Wv, Wo, x, WqkvT, WoT,
                                                  xb, use_xb, probe);
  gemm_qkv<<<dim3(NQKV / 128, M / 128), 256, 0, stream>>>(x, xb, use_xb, WqkvT,
                                                          Qb, Kb, Vt, cosb, sinb, probe);

  attn_kernel<<<dim3(8, BATCH * NH), 256, 0, stream>>>(Qb, Kb, Vt, AO);

  gemm_ao<<<dim3(DIM / 128, M / 128), 256, 0, stream>>>(AO, WoT, d_out, probe);
}

// Round 10
// 311.424 us; speedup vs baseline: 1.2420x; 1.0254x over previous
//
#include <hip/hip_runtime.h>
#include <hip/hip_bf16.h>

typedef unsigned short u16;
typedef unsigned int   u32;
typedef __bf16 bf16_t;
typedef bf16_t bf16x8 __attribute__((ext_vector_type(8)));
typedef u16    u16x8  __attribute__((ext_vector_type(8)));
typedef float  f32x4  __attribute__((ext_vector_type(4)));

#define DIM  2048
#define SEQ  2048
#define BATCH 2
#define NH   32
#define NKVH 8
#define HD   64
#define KVDIM (NKVH*HD)   // 512
#define NQKV (DIM + 2*KVDIM)  // 3072
#define SCALE 0.125f

__device__ __forceinline__ float b2f(u16 u) {
  union { u32 i; float f; } v; v.i = ((u32)u) << 16; return v.f;
}
__device__ __forceinline__ u16 f2b(float f) {
  union { float f; u32 i; } v; v.f = f;
  u32 x = v.i;
  return (u16)((x + 0x7fffu + ((x >> 16) & 1u)) >> 16);  // RNE
}
__device__ __forceinline__ u32 pkbf2(float a, float b) {  // low=a, high=b
  __hip_bfloat162 h = __float22bfloat162_rn(float2{a, b});
  union { __hip_bfloat162 h; u32 u; } v; v.h = h; return v.u;
}
__device__ __forceinline__ int probe_bf16(const u32* probe) { return probe[0] != 0u; }
__device__ __forceinline__ float ext_ld(const void* p, long idx, int mode_bf16) {
  return mode_bf16 ? b2f(((const u16*)p)[idx]) : ((const float*)p)[idx];
}
// 4 consecutive table values (fp32 float4 / bf16 ushort4); idx multiple of 4.
__device__ __forceinline__ f32x4 ld4(const void* p, long idx, int mode_bf16) {
  f32x4 r;
  if (mode_bf16) {
    ushort4 v = *(const ushort4*)((const u16*)p + idx);
    r[0] = b2f(v.x); r[1] = b2f(v.y); r[2] = b2f(v.z); r[3] = b2f(v.w);
  } else {
    float4 v = *(const float4*)((const float*)p + idx);
    r[0] = v.x; r[1] = v.y; r[2] = v.z; r[3] = v.w;
  }
  return r;
}
__device__ __forceinline__ void gload_lds16(const u16* g, u16* l) {
  __builtin_amdgcn_global_load_lds((const __attribute__((address_space(1))) void*)g,
                                   (__attribute__((address_space(3))) void*)l, 16, 0, 0);
}

// ---------------- merged prep: W transposes + x cast, one launch.
__global__ void prep(const void* __restrict__ Wq, const void* __restrict__ Wk,
                     const void* __restrict__ Wv, const void* __restrict__ Wo,
                     const void* __restrict__ x, u16* __restrict__ WqkvT,
                     u16* __restrict__ WoT, u16* __restrict__ xb, int use_xb,
                     const u32* __restrict__ probe) {
  int mode = probe_bf16(probe);
  int xt = blockIdx.x;
  int tx = threadIdx.x, ty = threadIdx.y;   // (32,8)
  if (xt < 160) {
    __shared__ u16 t[32][33];
    const void* in; int C, c0, obase; u16* out; int ld;
    if (xt < 64)       { in = Wq; C = DIM;   c0 = xt * 32;        obase = 0;           out = WqkvT; ld = DIM; }
    else if (xt < 80)  { in = Wk; C = KVDIM; c0 = (xt - 64) * 32; obase = DIM;         out = WqkvT; ld = DIM; }
    else if (xt < 96)  { in = Wv; C = KVDIM; c0 = (xt - 80) * 32; obase = DIM + KVDIM; out = WqkvT; ld = DIM; }
    else               { in = Wo; C = DIM;   c0 = (xt - 96) * 32; obase = 0;           out = WoT;   ld = DIM; }
    int r0 = blockIdx.y * 32;
#pragma unroll
    for (int i = 0; i < 32; i += 8)
      t[ty + i][tx] = mode ? ((const u16*)in)[(long)(r0 + ty + i) * C + c0 + tx]
                           : f2b(((const float*)in)[(long)(r0 + ty + i) * C + c0 + tx]);
    __syncthreads();
#pragma unroll
    for (int i = 0; i < 32; i += 8)
      out[(long)(obase + c0 + ty + i) * ld + r0 + tx] = t[tx][ty + i];
  } else {
    if (mode || !use_xb) return;
    int tid = ty * 32 + tx;
    long base = ((long)((xt - 160) * 64 + blockIdx.y) * 256 + tid) * 8;
    float4 f0 = *(const float4*)((const float*)x + base);
    float4 f1 = *(const float4*)((const float*)x + base + 4);
    u16x8 t8;
    t8[0] = f2b(f0.x); t8[1] = f2b(f0.y); t8[2] = f2b(f0.z); t8[3] = f2b(f0.w);
    t8[4] = f2b(f1.x); t8[5] = f2b(f1.y); t8[6] = f2b(f1.z); t8[7] = f2b(f1.w);
    *(u16x8*)&xb[base] = t8;
  }
}

// ======== 128x128 GEMM, BK=64 as TWO stacked BK=32 sub-tiles ========
// Each 128x32 half keeps the proven zero-conflict XOR-swizzled layout
// (BK=64 flat would be an 8-way bank conflict: row stride 128B = bank wrap).
// Halves the barrier count (32 iters instead of 64): the compiler-emitted
// vmcnt(0)+lgkmcnt(0) drain before each s_barrier is the ~20% structural
// stall of this GEMM class (m97 analysis); amortize it over 2x MFMA.
// SINGLE swapped kloop (n in reg dim). Q/K epilogue: FUSED RoPE.

__launch_bounds__(256)
__global__ void gemm_qkv(const void* __restrict__ x, const u16* __restrict__ xb,
                         int use_xb, const u16* __restrict__ Bt,
                         u16* __restrict__ Qb, u16* __restrict__ Kb, u16* __restrict__ Vt,
                         const void* __restrict__ cosb, const void* __restrict__ sinb,
                         const u32* __restrict__ probe) {
  int pmode = probe_bf16(probe);
  int mode = (use_xb || pmode) ? 1 : 0;
  const u16* A16 = pmode ? (const u16*)x : xb;
  const float* Af = (const float*)x;
  __shared__ __align__(16) u16 As[2 * 128 * 32];   // [half][row][32], 16 KB
  __shared__ __align__(16) u16 Bs[2 * 128 * 32];
  int tid = threadIdx.x, lane = tid & 63, wv = tid >> 6;
  int l16 = lane & 15, q = lane >> 4;
  int bm0 = blockIdx.y * 128, bn0 = blockIdx.x * 128;
  int mbase = (wv & 1) * 64, nbase = (wv >> 1) * 64;
  int c0 = tid, c1 = tid + 256;
  int r0 = c0 >> 2, s0 = (c0 & 3) ^ ((r0 >> 1) & 3);
  int r1 = c1 >> 2, s1 = (c1 & 3) ^ ((r1 >> 1) & 3);
  const int K = DIM;
  long aoff0 = (long)(bm0 + r0) * K + s0 * 8;
  long aoff1 = (long)(bm0 + r1) * K + s1 * 8;
  long boff0 = (long)(bn0 + r0) * K + s0 * 8;
  long boff1 = (long)(bn0 + r1) * K + s1 * 8;
  int rsw = (q ^ ((l16 >> 1) & 3)) * 8;
  f32x4 acc[4][4] = {};

  for (int k0 = 0; k0 < K; k0 += 64) {
    __syncthreads();
    if (mode) {
#pragma unroll
      for (int h = 0; h < 2; ++h) {
        gload_lds16(A16 + aoff0 + k0 + h * 32, &As[h * 4096 + wv * 512]);
        gload_lds16(A16 + aoff1 + k0 + h * 32, &As[h * 4096 + 2048 + wv * 512]);
      }
    } else {
#pragma unroll
      for (int h = 0; h < 2; ++h) {
        const float* p0 = Af + aoff0 + k0 + h * 32;
        float4 f0 = *(const float4*)p0;
        float4 f1 = *(const float4*)(p0 + 4);
        u16x8 t;
        t[0] = f2b(f0.x); t[1] = f2b(f0.y); t[2] = f2b(f0.z); t[3] = f2b(f0.w);
        t[4] = f2b(f1.x); t[5] = f2b(f1.y); t[6] = f2b(f1.z); t[7] = f2b(f1.w);
        *(u16x8*)&As[h * 4096 + c0 * 8] = t;
        const float* p1 = Af + aoff1 + k0 + h * 32;
        float4 g0 = *(const float4*)p1;
        float4 g1 = *(const float4*)(p1 + 4);
        u16x8 u;
        u[0] = f2b(g0.x); u[1] = f2b(g0.y); u[2] = f2b(g0.z); u[3] = f2b(g0.w);
        u[4] = f2b(g1.x); u[5] = f2b(g1.y); u[6] = f2b(g1.z); u[7] = f2b(g1.w);
        *(u16x8*)&As[h * 4096 + c1 * 8] = u;
      }
    }
#pragma unroll
    for (int h = 0; h < 2; ++h) {
      gload_lds16(Bt + boff0 + k0 + h * 32, &Bs[h * 4096 + wv * 512]);
      gload_lds16(Bt + boff1 + k0 + h * 32, &Bs[h * 4096 + 2048 + wv * 512]);
    }
    __syncthreads();
    bf16x8 af[4][2], bfr[4][2];
#pragma unroll
    for (int mi = 0; mi < 4; mi++)
#pragma unroll
      for (int h = 0; h < 2; ++h)
        af[mi][h] = *(const bf16x8*)&As[h * 4096 + (mbase + mi * 16 + l16) * 32 + rsw];
#pragma unroll
    for (int ni = 0; ni < 4; ni++)
#pragma unroll
      for (int h = 0; h < 2; ++h)
        bfr[ni][h] = *(const bf16x8*)&Bs[h * 4096 + (nbase + ni * 16 + l16) * 32 + rsw];
#pragma unroll
    for (int mi = 0; mi < 4; mi++)
#pragma unroll
      for (int ni = 0; ni < 4; ni++) {
        f32x4 z = acc[mi][ni];
        z = __builtin_amdgcn_mfma_f32_16x16x32_bf16(bfr[ni][0], af[mi][0], z, 0, 0, 0);
        z = __builtin_amdgcn_mfma_f32_16x16x32_bf16(bfr[ni][1], af[mi][1], z, 0, 0, 0);
        acc[mi][ni] = z;   // swapped: n in reg dim
      }
  }

  if (bn0 < DIM + KVDIM) {   // Q or K block: fused RoPE epilogue
    u16* Cb; int ldc, ncol0; float osc;
    if (bn0 < DIM) { Cb = Qb; ldc = DIM; ncol0 = bn0; osc = SCALE; }
    else           { Cb = Kb; ldc = KVDIM; ncol0 = bn0 - DIM; osc = 1.0f; }
#pragma unroll
    for (int mi = 0; mi < 4; mi++) {
      int m = bm0 + mbase + mi * 16 + l16;
      int st = m & (SEQ - 1);
#pragma unroll
      for (int ni = 0; ni < 2; ni++) {
        int dl = ni * 16 + q * 4;            // d in [0,32), 4 consecutive
        f32x4 c4 = ld4(cosb, (long)st * HD + dl, pmode);
        f32x4 s4 = ld4(sinb, (long)st * HD + dl, pmode);
        float lo[4], hi[4];
#pragma unroll
        for (int r = 0; r < 4; r++) {
          float a = acc[mi][ni][r], b = acc[mi][ni + 2][r];
          lo[r] = (a * c4[r] - b * s4[r]) * osc;
          hi[r] = (b * c4[r] + a * s4[r]) * osc;
        }
        int n0 = ncol0 + nbase + dl;
        uint2 w0, w1;
        w0.x = pkbf2(lo[0], lo[1]); w0.y = pkbf2(lo[2], lo[3]);
        w1.x = pkbf2(hi[0], hi[1]); w1.y = pkbf2(hi[2], hi[3]);
        *(uint2*)&Cb[(long)m * ldc + n0]      = w0;
        *(uint2*)&Cb[(long)m * ldc + n0 + 32] = w1;
      }
    }
  } else {                   // V block: transposed into Vt(B,KVH,64,S)
    int vcol0 = bn0 - DIM - KVDIM;
#pragma unroll
    for (int mi = 0; mi < 4; mi++) {
      int m = bm0 + mbase + mi * 16 + l16;
      int bb = m >> 11, s = m & (SEQ - 1);
#pragma unroll
      for (int ni = 0; ni < 4; ni++) {
        int vcol = vcol0 + nbase + ni * 16 + q * 4;
        int kvh2 = vcol >> 6, d = vcol & 63;
        long vb = ((long)(bb * NKVH + kvh2) * HD + d) * SEQ + s;
#pragma unroll
        for (int r = 0; r < 4; r++)
          Vt[vb + (long)r * SEQ] = f2b(acc[mi][ni][r]);
      }
    }
  }
}

// output projection: AO[M,2048] bf16 * WoT[2048,2048]^T -> C (ext dtype)
// BK=64 (two stacked BK=32 halves), swapped operands -> vectorized stores.
__launch_bounds__(256)
__global__ void gemm_ao(const u16* __restrict__ A, const u16* __restrict__ Bt,
                        void* __restrict__ C, const u32* __restrict__ probe) {
  int mode = probe_bf16(probe);
  __shared__ __align__(16) u16 As[2 * 128 * 32];
  __shared__ __align__(16) u16 Bs[2 * 128 * 32];
  int tid = threadIdx.x, lane = tid & 63, wv = tid >> 6;
  int l16 = lane & 15, q = lane >> 4;
  int bm0 = blockIdx.y * 128, bn0 = blockIdx.x * 128;
  int mbase = (wv & 1) * 64, nbase = (wv >> 1) * 64;
  int c0 = tid, c1 = tid + 256;
  int r0 = c0 >> 2, s0 = (c0 & 3) ^ ((r0 >> 1) & 3);
  int r1 = c1 >> 2, s1 = (c1 & 3) ^ ((r1 >> 1) & 3);
  const int K = DIM;
  long aoff0 = (long)(bm0 + r0) * K + s0 * 8;
  long aoff1 = (long)(bm0 + r1) * K + s1 * 8;
  long boff0 = (long)(bn0 + r0) * K + s0 * 8;
  long boff1 = (long)(bn0 + r1) * K + s1 * 8;
  int rsw = (q ^ ((l16 >> 1) & 3)) * 8;
  f32x4 acc[4][4] = {};
  for (int k0 = 0; k0 < K; k0 += 64) {
    __syncthreads();
#pragma unroll
    for (int h = 0; h < 2; ++h) {
      gload_lds16(A + aoff0 + k0 + h * 32, &As[h * 4096 + wv * 512]);
      gload_lds16(A + aoff1 + k0 + h * 32, &As[h * 4096 + 2048 + wv * 512]);
      gload_lds16(Bt + boff0 + k0 + h * 32, &Bs[h * 4096 + wv * 512]);
      gload_lds16(Bt + boff1 + k0 + h * 32, &Bs[h * 4096 + 2048 + wv * 512]);
    }
    __syncthreads();
    bf16x8 af[4][2], bfr[4][2];
#pragma unroll
    for (int mi = 0; mi < 4; mi++)
#pragma unroll
      for (int h = 0; h < 2; ++h)
        af[mi][h] = *(const bf16x8*)&As[h * 4096 + (mbase + mi * 16 + l16) * 32 + rsw];
#pragma unroll
    for (int ni = 0; ni < 4; ni++)
#pragma unroll
      for (int h = 0; h < 2; ++h)
        bfr[ni][h] = *(const bf16x8*)&Bs[h * 4096 + (nbase + ni * 16 + l16) * 32 + rsw];
#pragma unroll
    for (int mi = 0; mi < 4; mi++)
#pragma unroll
      for (int ni = 0; ni < 4; ni++) {
        f32x4 z = acc[mi][ni];
        z = __builtin_amdgcn_mfma_f32_16x16x32_bf16(bfr[ni][0], af[mi][0], z, 0, 0, 0);
        z = __builtin_amdgcn_mfma_f32_16x16x32_bf16(bfr[ni][1], af[mi][1], z, 0, 0, 0);
        acc[mi][ni] = z;   // swapped: n in reg dim
      }
  }
#pragma unroll
  for (int mi = 0; mi < 4; mi++)
#pragma unroll
    for (int ni = 0; ni < 4; ni++) {
      int m = bm0 + mbase + mi * 16 + l16;
      int n0 = bn0 + nbase + ni * 16 + q * 4;
      if (mode) {
        uint2 w;
        w.x = pkbf2(acc[mi][ni][0], acc[mi][ni][1]);
        w.y = pkbf2(acc[mi][ni][2], acc[mi][ni][3]);
        *(uint2*)&((u16*)C)[(long)m * DIM + n0] = w;
      } else {
        float4 f;
        f.x = acc[mi][ni][0]; f.y = acc[mi][ni][1];
        f.z = acc[mi][ni][2]; f.w = acc[mi][ni][3];
        *(float4*)&((float*)C)[(long)m * DIM + n0] = f;
      }
    }
}

// ---------------- fused causal attention, QBLK=128 (4 waves x 32 q-rows).
// R6/R9 best-measured configuration (319 us): double-buffered LDS K/V staging,
// one barrier per kv-tile, stage(kt+1) issued before compute(kt).
// grid (8, B*NH), diagonal pair {i, 15-i}; LDS 48 KB; 2 blocks/CU.
__launch_bounds__(256, 2)
__global__ void attn_kernel(const u16* __restrict__ Q, const u16* __restrict__ K,
                            const u16* __restrict__ Vt, u16* __restrict__ AO) {
  __shared__ __align__(16) u16 Ks[2 * 64 * 64];  // [buf][kv][d] swizzled
  __shared__ __align__(16) u16 Vs[2 * 64 * 64];  // [buf][d][kv] swizzled
  __shared__ __align__(16) u16 Ps[4][32 * 64];   // per-wave P (2 qr halves)
  int tid = threadIdx.x, lane = tid & 63, wv = tid >> 6;
  int l16 = lane & 15, q = lane >> 4;
  int i = blockIdx.x;          // 0..7
  int bh = blockIdx.y;
  int b = bh >> 5, h = bh & 31, kvh = h >> 2;
  const u16* Kp = K + (long)b * SEQ * KVDIM + kvh * HD;
  const u16* Vp = Vt + (long)(b * NKVH + kvh) * HD * SEQ;

  int cA = tid, cB = tid + 256;
  int rA = cA >> 3, bA = (cA & 7) ^ (rA & 7);
  int rB = cB >> 3, bB = (cB & 7) ^ (rB & 7);
  const u16* kSrcA = Kp + (long)rA * KVDIM + bA * 8;
  const u16* kSrcB = Kp + (long)rB * KVDIM + bB * 8;
  const u16* vSrcA = Vp + (long)rA * SEQ + bA * 8;
  const u16* vSrcB = Vp + (long)rB * SEQ + bB * 8;
  u16* kDstA = &Ks[(wv * 64 + lane) * 8];        // + buf offset (0 or 4096)
  u16* kDstB = &Ks[(256 + wv * 64 + lane) * 8];
  u16* vDstA = &Vs[(wv * 64 + lane) * 8];
  u16* vDstB = &Vs[(256 + wv * 64 + lane) * 8];

  int e = l16 & 7;
  int off0 = (q ^ e) * 8;          // logical block hh=0 (elems 0..31)
  int off1 = ((4 + q) ^ e) * 8;    // logical block hh=1 (elems 32..63)

  bf16x8 ones;
#pragma unroll
  for (int j = 0; j < 8; j++) ones[j] = (bf16_t)1.0f;

#pragma unroll
  for (int ph = 0; ph < 2; ph++) {
    int t = ph ? (15 - i) : i;
    int qbase = t * 128 + wv * 32;
    const u16* Qp = Q + (long)(b * SEQ + qbase) * DIM + h * HD;
    bf16x8 aq[2][2];
#pragma unroll
    for (int qr = 0; qr < 2; qr++) {
      aq[qr][0] = *(const bf16x8*)&Qp[(qr * 16 + l16) * DIM + q * 8];
      aq[qr][1] = *(const bf16x8*)&Qp[(qr * 16 + l16) * DIM + 32 + q * 8];
    }
    f32x4 o_acc[2][4] = {};
    f32x4 l_acc[2] = {};
    int nkt = 2 * (t + 1);
    int wmax = qbase + 31;       // wave's last q-row

    __syncthreads();   // all waves done reading LDS from previous phase
    gload_lds16(kSrcA, kDstA);
    gload_lds16(kSrcB, kDstB);
    gload_lds16(vSrcA, vDstA);
    gload_lds16(vSrcB, vDstB);
    int curo = 0;

    for (int kt = 0; kt < nkt; kt++) {
      __syncthreads();   // drains vmcnt: buf[curo] staged; prev reads complete
      if (kt + 1 < nkt) {   // stage next tile into the other buffer
        long kk2 = (long)(kt + 1) * 64;
        int nxt = curo ^ 4096;
        gload_lds16(kSrcA + kk2 * KVDIM, kDstA + nxt);
        gload_lds16(kSrcB + kk2 * KVDIM, kDstB + nxt);
        gload_lds16(vSrcA + kk2, vDstA + nxt);
        gload_lds16(vSrcB + kk2, vDstB + nxt);
      }
      int kk = kt * 64;
      if (kk > wmax) { curo ^= 4096; continue; }   // wave fully masked (uniform)
      const u16* Ksb = &Ks[curo];
      const u16* Vsb = &Vs[curo];

      bf16x8 bk[4][2], bv[4][2];
#pragma unroll
      for (int ni = 0; ni < 4; ni++) {
        bk[ni][0] = *(const bf16x8*)&Ksb[(ni * 16 + l16) * 64 + off0];
        bk[ni][1] = *(const bf16x8*)&Ksb[(ni * 16 + l16) * 64 + off1];
      }
#pragma unroll
      for (int di = 0; di < 4; di++) {
        bv[di][0] = *(const bf16x8*)&Vsb[(di * 16 + l16) * 64 + off0];
        bv[di][1] = *(const bf16x8*)&Vsb[(di * 16 + l16) * 64 + off1];
      }
      bool diag = (kt >= 2 * t);
#pragma unroll
      for (int qr = 0; qr < 2; qr++) {
        int qb16 = qbase + qr * 16;
        if (kk > qb16 + 15) continue;   // half fully masked (uniform per wave)
        f32x4 sc[4];
#pragma unroll
        for (int ni = 0; ni < 4; ni++) {
          f32x4 z = {};
          z = __builtin_amdgcn_mfma_f32_16x16x32_bf16(bk[ni][0], aq[qr][0], z, 0, 0, 0);
          z = __builtin_amdgcn_mfma_f32_16x16x32_bf16(bk[ni][1], aq[qr][1], z, 0, 0, 0);
          sc[ni] = z;
        }
        int qrow = qb16 + l16;
        if (diag) {
#pragma unroll
          for (int ni = 0; ni < 4; ni++)
#pragma unroll
            for (int r = 0; r < 4; r++) {
              int kv = kk + ni * 16 + q * 4 + r;
              float p = __expf(sc[ni][r]);
              sc[ni][r] = (kv <= qrow) ? p : 0.f;
            }
        } else {
#pragma unroll
          for (int ni = 0; ni < 4; ni++)
#pragma unroll
            for (int r = 0; r < 4; r++) sc[ni][r] = __expf(sc[ni][r]);
        }
#pragma unroll
        for (int ni = 0; ni < 4; ni++) {
          uint2 w;
          w.x = pkbf2(sc[ni][0], sc[ni][1]);
          w.y = pkbf2(sc[ni][2], sc[ni][3]);
          int pblk = (2 * ni + (q >> 1)) ^ e;
          *(uint2*)&Ps[wv][(qr * 16 + l16) * 64 + pblk * 8 + (q & 1) * 4] = w;
        }
        bf16x8 ap0 = *(const bf16x8*)&Ps[wv][(qr * 16 + l16) * 64 + off0];
        bf16x8 ap1 = *(const bf16x8*)&Ps[wv][(qr * 16 + l16) * 64 + off1];
        l_acc[qr] = __builtin_amdgcn_mfma_f32_16x16x32_bf16(ap0, ones, l_acc[qr], 0, 0, 0);
        l_acc[qr] = __builtin_amdgcn_mfma_f32_16x16x32_bf16(ap1, ones, l_acc[qr], 0, 0, 0);
#pragma unroll
        for (int di = 0; di < 4; di++) {
          o_acc[qr][di] = __builtin_amdgcn_mfma_f32_16x16x32_bf16(ap0, bv[di][0], o_acc[qr][di], 0, 0, 0);
          o_acc[qr][di] = __builtin_amdgcn_mfma_f32_16x16x32_bf16(ap1, bv[di][1], o_acc[qr][di], 0, 0, 0);
        }
      }
      curo ^= 4096;
    }
#pragma unroll
    for (int qr = 0; qr < 2; qr++) {
      long obase = (long)(b * SEQ + qbase + qr * 16 + q * 4) * DIM + h * HD;
#pragma unroll
      for (int r = 0; r < 4; r++) {
        float inv = 1.0f / l_acc[qr][r];
#pragma unroll
        for (int di = 0; di < 4; di++)
          AO[obase + (long)r * DIM + di * 16 + l16] = f2b(o_acc[qr][di][r] * inv);
      }
    }
  }
}

extern "C" void kernel_launch(void* const* d_in, const int* in_sizes, int n_in,
                              void* d_out, int out_size, void* d_ws, size_t ws_size,
                              hipStream_t stream) {
  const void* x    = d_in[0];
  const void* Wq   = d_in[1];
  const void* Wk   = d_in[2];
  const void* Wv   = d_in[3];
  const void* Wo   = d_in[4];
  const void* cosb = d_in[5];
  const void* sinb = d_in[6];
  const u32*  probe = (const u32*)d_in[7];

  // workspace: WqkvT 12M + WoT 8M + Qb 16M + Kb 4M + Vt 4M (=44M) + xb 16M opt
  u16* WqkvT = (u16*)d_ws;
  u16* WoT = WqkvT + (size_t)NQKV * DIM;
  u16* Qb  = WoT + (size_t)DIM * DIM;
  u16* Kb  = Qb  + (size_t)BATCH * SEQ * DIM;
  u16* Vt  = Kb  + (size_t)BATCH * SEQ * KVDIM;
  u16* xb  = Vt  + (size_t)BATCH * NKVH * HD * SEQ;
  u16* AO  = Qb;   // alias: each attn wave reads its own Q rows before writing them

  size_t need_xb = ((size_t)(xb - WqkvT) + (size_t)BATCH * SEQ * DIM) * sizeof(u16);
  int use_xb = ws_size >= need_xb;

  int M = BATCH * SEQ;  // 4096
  prep<<<dim3(224, 64), dim3(32, 8), 0, stream>>>(Wq, Wk, Wv, Wo, x, WqkvT, WoT,
                                                  xb, use_xb, probe);
  gemm_qkv<<<dim3(NQKV / 128, M / 128), 256, 0, stream>>>(x, xb, use_xb, WqkvT,
                                                          Qb, Kb, Vt, cosb, sinb, probe);

  attn_kernel<<<dim3(8, BATCH * NH), 256, 0, stream>>>(Qb, Kb, Vt, AO);

  gemm_ao<<<dim3(DIM / 128, M / 128), 256, 0, stream>>>(AO, WoT, d_out, probe);
}